// Round 1
// baseline (5307.341 us; speedup 1.0000x reference)
//
#include <hip/hip_runtime.h>
#include <stdint.h>
#include <stddef.h>

typedef uint32_t u32;
typedef float v2f __attribute__((ext_vector_type(2)));

// ---------------- problem constants (fixed by reference file) ----------------
#define NB    256      // batch B
#define LFULL 412      // L
#define NCH   3        // C
#define CTX   336      // context_length
#define NSAMP 100      // n_samples
#define TM1   383      // T-1 (T = L - MAX_LAG = 384)
#define HID   64
#define NIN   15
#define RTOT  25600    // NB*NSAMP
#define NCTXS 8601600u // RTOT*CTX
#define NSTEP 47       // H-1

#define DROWS   16     // rows per persistent decode block (4 per wave)
#define DBLOCKS (RTOT / DROWS)  // 1600

#define JAX_PARTITIONABLE 1

__device__ const int c_LAGS[10] = {1,2,3,4,5,6,7,14,21,28};

__device__ inline v2f bc2(float x) { v2f r; r[0] = x; r[1] = x; return r; }

// ---------------- threefry2x32 (matches jax._src.prng) ----------------
__host__ __device__ inline void tf2x32(u32 k0, u32 k1, u32 x0, u32 x1, u32& o0, u32& o1) {
  const u32 ks2 = k0 ^ k1 ^ 0x1BD11BDAu;
#define TFR(r) { x0 += x1; x1 = (x1 << (r)) | (x1 >> (32 - (r))); x1 ^= x0; }
  x0 += k0; x1 += k1;
  TFR(13) TFR(15) TFR(26) TFR(6)
  x0 += k1; x1 += ks2 + 1u;
  TFR(17) TFR(29) TFR(16) TFR(24)
  x0 += ks2; x1 += k0 + 2u;
  TFR(13) TFR(15) TFR(26) TFR(6)
  x0 += k0; x1 += k1 + 3u;
  TFR(17) TFR(29) TFR(16) TFR(24)
  x0 += k1; x1 += ks2 + 4u;
  TFR(13) TFR(15) TFR(26) TFR(6)
  x0 += ks2; x1 += k0 + 5u;
#undef TFR
  o0 = x0; o1 = x1;
}

__host__ __device__ inline u32 split_word_legacy(u32 k0, u32 k1, u32 n, u32 j) {
  u32 o0, o1;
  if (j < n) { tf2x32(k0, k1, j, n + j, o0, o1); return o0; }
  tf2x32(k0, k1, j - n, j, o0, o1); return o1;
}

__host__ __device__ inline void jx_subkey(u32 k0, u32 k1, u32 n, u32 i, u32& s0, u32& s1) {
#if JAX_PARTITIONABLE
  (void)n; tf2x32(k0, k1, 0u, i, s0, s1);
#else
  s0 = split_word_legacy(k0, k1, n, 2u * i);
  s1 = split_word_legacy(k0, k1, n, 2u * i + 1u);
#endif
}

__device__ inline u32 jx_bits(u32 k0, u32 k1, u32 n, u32 i) {
#if JAX_PARTITIONABLE
  (void)n; u32 o0, o1; tf2x32(k0, k1, 0u, i, o0, o1); return o0 ^ o1;
#else
  u32 o0, o1;
  if (n == 1u) { tf2x32(k0, k1, 0u, 0u, o0, o1); return o0; }
  const u32 h = n >> 1;
  if (i < h) { tf2x32(k0, k1, i, h + i, o0, o1); return o0; }
  tf2x32(k0, k1, i - h, i, o0, o1); return o1;
#endif
}

// ---------------- JAX-exact float transforms ----------------
__device__ inline float jax_erfinv(float x) {
#pragma clang fp contract(off)
  float w = -log1pf(-x * x);
  float p;
  if (w < 5.0f) {
    w = w - 2.5f;
    p = 2.81022636e-08f;
    p = 3.43273939e-07f + p * w;
    p = -3.5233877e-06f + p * w;
    p = -4.39150654e-06f + p * w;
    p = 0.00021858087f + p * w;
    p = -0.00125372503f + p * w;
    p = -0.00417768164f + p * w;
    p = 0.246640727f + p * w;
    p = 1.50140941f + p * w;
  } else {
    w = sqrtf(w) - 3.0f;
    p = -0.000200214257f;
    p = 0.000100950558f + p * w;
    p = 0.00134934322f + p * w;
    p = -0.00367342844f + p * w;
    p = 0.00573950773f + p * w;
    p = -0.0076224613f + p * w;
    p = 0.00943887047f + p * w;
    p = 1.00167406f + p * w;
    p = 2.83297682f + p * w;
  }
  return p * x;
}

__device__ inline float u01_from_bits(u32 bits) {
  return __uint_as_float((bits >> 9) | 0x3f800000u) - 1.0f;
}

__device__ inline float normal_from_bits(u32 bits) {
#pragma clang fp contract(off)
  const float lo = -0.99999994f;
  const float u = u01_from_bits(bits);
  float r = u * 2.0f + lo;
  r = fmaxf(lo, r);
  return 1.41421356f * jax_erfinv(r);
}

__device__ float jax_gamma_one(u32 k0, u32 k1, float alpha) {
#pragma clang fp contract(off)
  const bool boost_mask = (alpha >= 1.0f);
  const float alpha_orig = alpha;
  const float a = boost_mask ? alpha : (alpha + 1.0f);
  const float d = a - 0.33333334f;
  const float c = 0.33333334f / sqrtf(d);
  u32 K0, K1, S0, S1;
  jx_subkey(k0, k1, 2u, 0u, K0, K1);
  jx_subkey(k0, k1, 2u, 1u, S0, S1);
  float u_boost = 1.0f;
  if (!boost_mask) u_boost = u01_from_bits(jx_bits(S0, S1, 1u, 0u));
  float X = 0.0f, V = 1.0f, U = 2.0f;
  while (true) {
    if (!(U >= 1.0f - 0.0331f * (X * X))) break;
    if (!(logf(U) >= 0.5f * X + d * ((1.0f - V) + logf(V)))) break;
    u32 nk0, nk1, xk0, xk1, uk0, uk1;
    jx_subkey(K0, K1, 3u, 0u, nk0, nk1);
    jx_subkey(K0, K1, 3u, 1u, xk0, xk1);
    jx_subkey(K0, K1, 3u, 2u, uk0, uk1);
    K0 = nk0; K1 = nk1;
    float x, v;
    u32 c0 = xk0, c1 = xk1;
    do {
      u32 t0, t1, s0, s1;
      jx_subkey(c0, c1, 2u, 0u, t0, t1);
      jx_subkey(c0, c1, 2u, 1u, s0, s1);
      c0 = t0; c1 = t1;
      x = normal_from_bits(jx_bits(s0, s1, 1u, 0u));
      v = 1.0f + x * c;
    } while (v <= 0.0f);
    X = x * x;
    V = (v * v) * v;
    U = u01_from_bits(jx_bits(uk0, uk1, 1u, 0u));
  }
  const float sample = d * V;
  const float boost = boost_mask ? 1.0f : powf(u_boost, 1.0f / alpha_orig);
  return sample * boost;
}

__device__ inline float sigm(float x) { return 1.0f / (1.0f + expf(-x)); }
__device__ inline float softplusf(float x) { return fmaxf(x, 0.0f) + log1pf(expf(-fabsf(x))); }

// cross-lane broadcast on the VALU pipe (not DS): v_readlane -> SGPR (ctx kernel)
__device__ inline float rl_f(float v, int l) {
  return __int_as_float(__builtin_amdgcn_readlane(__float_as_int(v), l));
}

// ---------------- workspace layout (floats) ----------------
enum : size_t {
  OFF_INP  = 0,
  OFF_CT   = OFF_INP + (size_t)NB * TM1 * NIN,
  OFF_TS   = OFF_CT + (size_t)NB * CTX,
  OFF_LTS  = OFF_TS + NB,
  OFF_DF   = OFF_LTS + NB,
  OFF_LOC  = OFF_DF + (size_t)NB * CTX,
  OFF_SC   = OFF_LOC + (size_t)NB * CTX,
  OFF_H0F  = OFF_SC + (size_t)NB * CTX,
  OFF_C0F  = OFF_H0F + (size_t)NB * HID,
  OFF_H1F  = OFF_C0F + (size_t)NB * HID,
  OFF_C1F  = OFF_H1F + (size_t)NB * HID,
  OFF_YH   = OFF_C1F + (size_t)NB * HID,
  OFF_WTX  = OFF_YH + (size_t)RTOT * TM1,     // Wih0^T padded [16][256] (ctx kernel)
  OFF_WT00 = OFF_WTX + 4096,                  // Whh0^T [64][256]
  OFF_WT10 = OFF_WT00 + 16384,                // Wih1^T [64][256]
  OFF_WT11 = OFF_WT10 + 16384,                // Whh1^T [64][256]
  OFF_WPX  = OFF_WT11 + 16384,                // k-pair-interleaved layouts (dec kernel)
  OFF_WP00 = OFF_WPX + 4096,
  OFF_WP10 = OFF_WP00 + 16384,
  OFF_WP11 = OFF_WP10 + 16384,
  OFF_RND  = OFF_WP11 + 16384,                // decode randoms [NSTEP][RTOT][4]
  WS_FLOATS = OFF_RND + (size_t)NSTEP * RTOT * 4
};

// ---------------- kernel 0a: transpose weights ------------------------------
// Plain layout [k][256] for ctx kernel, plus k-pair-interleaved layout for the
// decode kernel:  float index p:  kp=p>>9; rem=p&511; part=rem>>8;
// l=(rem>>2)&63; f=rem&3;  gate g = 4*l + 2*part + (f>>1); k = 2*kp + (f&1).
// This makes each lane's per-kpair 16B weight read sit at 16B lane stride
// (bank-conflict-free ds_read_b128) and pairs k-even/k-odd for v_pk_fma_f32.
__global__ void __launch_bounds__(256) wtrans_kernel(
    const float* __restrict__ Wih0, const float* __restrict__ Whh0,
    const float* __restrict__ Wih1, const float* __restrict__ Whh1,
    float* __restrict__ WTx, float* __restrict__ WT00,
    float* __restrict__ WT10, float* __restrict__ WT11,
    float* __restrict__ WPX, float* __restrict__ WP00,
    float* __restrict__ WP10, float* __restrict__ WP11)
{
  const int i = blockIdx.x * 256 + threadIdx.x;   // < 106496
  if (i < 53248) {
    if (i < 4096) {
      const int k = i >> 8, g = i & 255;
      WTx[i] = (k < 15) ? Wih0[g * 15 + k] : 0.0f;
    } else if (i < 4096 + 16384) {
      const int j = i - 4096, k = j >> 8, g = j & 255;
      WT00[j] = Whh0[g * 64 + k];
    } else if (i < 4096 + 32768) {
      const int j = i - 4096 - 16384, k = j >> 8, g = j & 255;
      WT10[j] = Wih1[g * 64 + k];
    } else {
      const int j = i - 4096 - 32768, k = j >> 8, g = j & 255;
      WT11[j] = Whh1[g * 64 + k];
    }
  } else {
    const int p = i - 53248;
    if (p < 4096) {
      const int kp = p >> 9, rem = p & 511;
      const int part = rem >> 8, l = (rem >> 2) & 63, f = rem & 3;
      const int g = l * 4 + part * 2 + (f >> 1), k = kp * 2 + (f & 1);
      WPX[p] = (k < 15) ? Wih0[g * 15 + k] : 0.0f;
    } else if (p < 20480) {
      const int q = p - 4096;
      const int kp = q >> 9, rem = q & 511;
      const int part = rem >> 8, l = (rem >> 2) & 63, f = rem & 3;
      const int g = l * 4 + part * 2 + (f >> 1), k = kp * 2 + (f & 1);
      WP00[q] = Whh0[g * 64 + k];
    } else if (p < 36864) {
      const int q = p - 20480;
      const int kp = q >> 9, rem = q & 511;
      const int part = rem >> 8, l = (rem >> 2) & 63, f = rem & 3;
      const int g = l * 4 + part * 2 + (f >> 1), k = kp * 2 + (f & 1);
      WP10[q] = Wih1[g * 64 + k];
    } else {
      const int q = p - 36864;
      const int kp = q >> 9, rem = q & 511;
      const int part = rem >> 8, l = (rem >> 2) & 63, f = rem & 3;
      const int g = l * 4 + part * 2 + (f >> 1), k = kp * 2 + (f & 1);
      WP11[q] = Whh1[g * 64 + k];
    }
  }
}

// ---------------- kernel 0b: precompute decode randoms -----------------------
__global__ void __launch_bounds__(256) rnd_dec_kernel(
    float* __restrict__ RND, u32 kl0, u32 kl1)
{
  const int i = blockIdx.x * 256 + threadIdx.x;   // < NSTEP*RTOT = 1203200
  const int s = i / RTOT, rg = i - s * RTOT;
  u32 ks0, ks1, skz0, skz1, skg0, skg1;
  tf2x32(kl0, kl1, 0u, (u32)s, ks0, ks1);
  tf2x32(ks0, ks1, 0u, 0u, skz0, skz1);
  tf2x32(ks0, ks1, 0u, 1u, skg0, skg1);
  const float z = normal_from_bits(jx_bits(skz0, skz1, RTOT, (u32)rg));
  u32 gk0, gk1;
  jx_subkey(skg0, skg1, RTOT, (u32)rg, gk0, gk1);
  u32 K0, K1, S0, S1;
  jx_subkey(gk0, gk1, 2u, 0u, K0, K1);
  jx_subkey(gk0, gk1, 2u, 1u, S0, S1);   // boost key, unused (alpha >= 1)
  u32 nk0, nk1, xk0, xk1, uk0, uk1;
  jx_subkey(K0, K1, 3u, 0u, nk0, nk1);
  jx_subkey(K0, K1, 3u, 1u, xk0, xk1);
  jx_subkey(K0, K1, 3u, 2u, uk0, uk1);
  u32 c0 = xk0, c1 = xk1, t0, t1, s0, s1;
  jx_subkey(c0, c1, 2u, 0u, t0, t1);
  jx_subkey(c0, c1, 2u, 1u, s0, s1);
  const float x1 = normal_from_bits(jx_bits(s0, s1, 1u, 0u));
  c0 = t0; c1 = t1;
  jx_subkey(c0, c1, 2u, 0u, t0, t1);
  jx_subkey(c0, c1, 2u, 1u, s0, s1);
  const float x2 = normal_from_bits(jx_bits(s0, s1, 1u, 0u));
  const float U1 = u01_from_bits(jx_bits(uk0, uk1, 1u, 0u));
  float* R = RND + (size_t)i * 4;
  R[0] = z; R[1] = x1; R[2] = x2; R[3] = U1;
}

// ---------------- kernel 1: tscale + feature build ----------------
__global__ void __launch_bounds__(256) prep_kernel(
    const float* __restrict__ X, const float* __restrict__ emb,
    float* __restrict__ inp, float* __restrict__ ct,
    float* __restrict__ tscale, float* __restrict__ ltscale)
{
  const int b = blockIdx.x, t = threadIdx.x;
  __shared__ float red[256];
  __shared__ float ts_sh;
  const float* Xb = X + (size_t)b * LFULL * NCH;
  float p = fabsf(Xb[(28 + t) * NCH]);
  if (t < 80) p += fabsf(Xb[(28 + 256 + t) * NCH]);
  red[t] = p;
  for (int st = 128; st > 0; st >>= 1) { __syncthreads(); if (t < st) red[t] += red[t + st]; }
  __syncthreads();
  if (t == 0) {
    float ts = red[0] / 336.0f;
    ts = fmaxf(ts, 1e-10f);
    tscale[b] = ts; ltscale[b] = logf(ts); ts_sh = ts;
  }
  __syncthreads();
  const float ts = ts_sh;
  const float lts = logf(ts);
  const float ev = emb[0];
  for (int idx = t; idx < TM1 * NIN; idx += 256) {
    const int tt = idx / NIN, f = idx - tt * NIN;
    float val;
    if (f == 0)       val = (tt < CTX) ? Xb[(28 + tt) * NCH] / ts : 0.0f;
    else if (f <= 10) val = (tt < CTX) ? Xb[(28 + tt - c_LAGS[f - 1]) * NCH] / ts : 0.0f;
    else if (f == 11) val = ev;
    else if (f == 12) val = Xb[(28 + tt) * NCH + 2];
    else if (f == 13) val = lts;
    else              val = Xb[(28 + tt) * NCH + 1];
    inp[(size_t)(b * TM1 + tt) * NIN + f] = val;
    if (f == 0 && tt < CTX) ct[b * CTX + tt] = val;
  }
}

// ---------------- kernel 2: context LSTM (unchanged) -------------------------
__global__ void __launch_bounds__(256) ctx_lstm_kernel(
    const float* __restrict__ inp,
    const float* __restrict__ WTx, const float* __restrict__ WT00,
    const float* __restrict__ WT10, const float* __restrict__ WT11,
    const float* __restrict__ bih0, const float* __restrict__ bhh0,
    const float* __restrict__ bih1, const float* __restrict__ bhh1,
    const float* __restrict__ wdf, const float* __restrict__ bdfp,
    const float* __restrict__ wloc, const float* __restrict__ blocp,
    const float* __restrict__ wsc, const float* __restrict__ bscp,
    float* __restrict__ dfo, float* __restrict__ loco, float* __restrict__ sco,
    float* __restrict__ h0f, float* __restrict__ c0f,
    float* __restrict__ h1f, float* __restrict__ c1f)
{
  const int b = blockIdx.x, t = threadIdx.x;
  const int lane = t & 63, w = t >> 6;
  const int gbase = lane << 2;
  __shared__ __align__(16) float gA[4][256];
  __shared__ __align__(16) float gB[4][256];

  const float bs0 = bih0[lane]       + bhh0[lane];
  const float bs1 = bih0[64 + lane]  + bhh0[64 + lane];
  const float bs2 = bih0[128 + lane] + bhh0[128 + lane];
  const float bs3 = bih0[192 + lane] + bhh0[192 + lane];
  const float bs4 = bih1[lane]       + bhh1[lane];
  const float bs5 = bih1[64 + lane]  + bhh1[64 + lane];
  const float bs6 = bih1[128 + lane] + bhh1[128 + lane];
  const float bs7 = bih1[192 + lane] + bhh1[192 + lane];
  const float wdfv = wdf[lane], wlocv = wloc[lane], wscv = wsc[lane];
  const float bdf = bdfp[0], bloc = blocp[0], bsc = bscp[0];

  float h0r = 0.f, h1r = 0.f, c0r = 0.f, c1r = 0.f;
  const float* inb = inp + (size_t)b * TM1 * NIN;
  const int kx = w * 4;    // x-part k-quarter
  const int kh = w * 16;   // h-part k-quarter

  for (int tt = 0; tt < CTX; tt++) {
    float xr = 0.f;
    if (lane < 15) xr = inb[tt * NIN + lane];

    v2f aA = bc2(0.0f), aB = bc2(0.0f);
#pragma unroll
    for (int kk = 0; kk < 4; kk++) {
      const int k = kx + kk;
      const float4 wv = *(const float4*)&WTx[(k << 8) + gbase];
      v2f wlo, whi; wlo[0] = wv.x; wlo[1] = wv.y; whi[0] = wv.z; whi[1] = wv.w;
      const v2f hk = bc2(rl_f(xr, k));
      aA += wlo * hk; aB += whi * hk;
    }
#pragma unroll
    for (int kk = 0; kk < 16; kk++) {
      const int k = kh + kk;
      const float4 wv = *(const float4*)&WT00[(k << 8) + gbase];
      v2f wlo, whi; wlo[0] = wv.x; wlo[1] = wv.y; whi[0] = wv.z; whi[1] = wv.w;
      const v2f hk = bc2(rl_f(h0r, k));
      aA += wlo * hk; aB += whi * hk;
    }
    {
      float4 gv; gv.x = aA[0]; gv.y = aA[1]; gv.z = aB[0]; gv.w = aB[1];
      *(float4*)&gA[w][gbase] = gv;
    }
    __syncthreads();

    {
      float gi = ((gA[0][lane]       + gA[1][lane])       + gA[2][lane])       + gA[3][lane];
      float gf = ((gA[0][64 + lane]  + gA[1][64 + lane])  + gA[2][64 + lane])  + gA[3][64 + lane];
      float gg = ((gA[0][128 + lane] + gA[1][128 + lane]) + gA[2][128 + lane]) + gA[3][128 + lane];
      float go = ((gA[0][192 + lane] + gA[1][192 + lane]) + gA[2][192 + lane]) + gA[3][192 + lane];
      gi += bs0; gf += bs1; gg += bs2; go += bs3;
      c0r = sigm(gf) * c0r + sigm(gi) * tanhf(gg);
      h0r = sigm(go) * tanhf(c0r);
    }

    aA = bc2(0.0f); aB = bc2(0.0f);
#pragma unroll
    for (int kk = 0; kk < 16; kk++) {
      const int k = kh + kk;
      const float4 wv = *(const float4*)&WT10[(k << 8) + gbase];
      v2f wlo, whi; wlo[0] = wv.x; wlo[1] = wv.y; whi[0] = wv.z; whi[1] = wv.w;
      const v2f hk = bc2(rl_f(h0r, k));
      aA += wlo * hk; aB += whi * hk;
    }
#pragma unroll
    for (int kk = 0; kk < 16; kk++) {
      const int k = kh + kk;
      const float4 wv = *(const float4*)&WT11[(k << 8) + gbase];
      v2f wlo, whi; wlo[0] = wv.x; wlo[1] = wv.y; whi[0] = wv.z; whi[1] = wv.w;
      const v2f hk = bc2(rl_f(h1r, k));
      aA += wlo * hk; aB += whi * hk;
    }
    {
      float4 gv; gv.x = aA[0]; gv.y = aA[1]; gv.z = aB[0]; gv.w = aB[1];
      *(float4*)&gB[w][gbase] = gv;
    }
    __syncthreads();

    {
      float gi = ((gB[0][lane]       + gB[1][lane])       + gB[2][lane])       + gB[3][lane];
      float gf = ((gB[0][64 + lane]  + gB[1][64 + lane])  + gB[2][64 + lane])  + gB[3][64 + lane];
      float gg = ((gB[0][128 + lane] + gB[1][128 + lane]) + gB[2][128 + lane]) + gB[3][128 + lane];
      float go = ((gB[0][192 + lane] + gB[1][192 + lane]) + gB[2][192 + lane]) + gB[3][192 + lane];
      gi += bs4; gf += bs5; gg += bs6; go += bs7;
      c1r = sigm(gf) * c1r + sigm(gi) * tanhf(gg);
      h1r = sigm(go) * tanhf(c1r);
      if (w == 0) {
        float pd = h1r * wdfv, pl = h1r * wlocv, ps = h1r * wscv;
#pragma unroll
        for (int off = 32; off > 0; off >>= 1) {
          pd += __shfl_down(pd, off, 64);
          pl += __shfl_down(pl, off, 64);
          ps += __shfl_down(ps, off, 64);
        }
        if (lane == 0) {
          dfo[b * CTX + tt]  = 2.0f + softplusf(pd + bdf);
          loco[b * CTX + tt] = pl + bloc;
          sco[b * CTX + tt]  = softplusf(ps + bsc);
        }
      }
    }
  }
  if (w == 0) {
    h0f[b * 64 + lane] = h0r; c0f[b * 64 + lane] = c0r;
    h1f[b * 64 + lane] = h1r; c1f[b * 64 + lane] = c1r;
  }
}

// ---------------- kernel 3: context sampling (y_ctx) ----------------
__global__ void __launch_bounds__(256) ctx_sample_kernel(
    const float* __restrict__ df, const float* __restrict__ loc, const float* __restrict__ sc,
    const float* __restrict__ tscale, float* __restrict__ yhat,
    u32 kz0, u32 kz1, u32 kg0, u32 kg1)
{
  const int i = blockIdx.x * 256 + threadIdx.x;
  const int r = i / CTX, t = i - r * CTX;
  const int b = r / NSAMP;
  const float dfv = df[b * CTX + t], lv = loc[b * CTX + t], sv = sc[b * CTX + t];
  const float z = normal_from_bits(jx_bits(kz0, kz1, NCTXS, (u32)i));
  u32 gk0, gk1;
  jx_subkey(kg0, kg1, NCTXS, (u32)i, gk0, gk1);
  const float g = jax_gamma_one(gk0, gk1, dfv * 0.5f);
  const float y = (lv + sv * (z * sqrtf(dfv / (2.0f * g)))) * tscale[b];
  yhat[(size_t)r * TM1 + t] = y;
}

// ---------------- decode helpers ---------------------------------------------
// cooperative 16KB chunk stage: wave w copies quarter w, 4 x (64 lanes x 16B)
__device__ __forceinline__ void stage16k(const float* __restrict__ src,
                                         float* dst, int w, int lane)
{
#pragma unroll
  for (int i = 0; i < 4; i++) {
    __builtin_amdgcn_global_load_lds(
        (const __attribute__((address_space(1))) void*)(src + (size_t)w * 1024 + i * 256 + lane * 4),
        (__attribute__((address_space(3))) void*)(dst + w * 1024 + i * 256),
        16, 0, 0);
  }
}

// one staged 16KB chunk = 8 kpairs x 256 gates x {k-even,k-odd}.
// weights: 2 bank-conflict-free ds_read_b128 per kpair (16B lane stride);
// h operand: uniform-address ds_read_b64 broadcast per (row, kpair) -> pk_fma.
__device__ __forceinline__ void chunk_mac(const float* __restrict__ wb,
                                          const float* __restrict__ hop,
                                          const int hstride, const int kp0,
                                          v2f (&acc)[4][4],
                                          const int r0, const int lane)
{
#pragma unroll
  for (int j = 0; j < 8; j++) {
    const float4 wv0 = *(const float4*)&wb[j * 512 + (lane << 2)];
    const float4 wv1 = *(const float4*)&wb[j * 512 + 256 + (lane << 2)];
    v2f w0, w1, w2, w3;
    w0[0] = wv0.x; w0[1] = wv0.y;  w1[0] = wv0.z; w1[1] = wv0.w;
    w2[0] = wv1.x; w2[1] = wv1.y;  w3[0] = wv1.z; w3[1] = wv1.w;
#pragma unroll
    for (int rr = 0; rr < 4; rr++) {
      const v2f hp = *(const v2f*)&hop[(r0 + rr) * hstride + ((kp0 + j) << 1)];
      acc[rr][0] += w0 * hp;
      acc[rr][1] += w1 * hp;
      acc[rr][2] += w2 * hp;
      acc[rr][3] += w3 * hp;
    }
  }
}

// ---------------- kernel 5: persistent decode (LDS-staged weights) ----------
// R0 of this session: the old kernel streamed 208KB of weights from L2 per
// wave per step (working set >> 32KB L1) and spent ~20% of VALU issue on
// v_readlane h-broadcasts.  Now: 13 double-buffered 16KB weight chunks per
// step staged block-cooperatively via global_load_lds (L2 traffic /4, inner
// loop reads are conflict-free ds_read_b128), and h/x broadcasts are
// uniform-address ds_read_b64 k-pairs feeding v_pk_fma_f32 (zero VALU cost).
// LDS 62.8KB -> 2 blocks/CU.
__global__ void __launch_bounds__(256) dec_persist_kernel(
    const float* __restrict__ inp, const float* __restrict__ tscale,
    const float* __restrict__ WPX, const float* __restrict__ WP00,
    const float* __restrict__ WP10, const float* __restrict__ WP11,
    const float* __restrict__ bih0, const float* __restrict__ bhh0,
    const float* __restrict__ bih1, const float* __restrict__ bhh1,
    const float* __restrict__ wdf, const float* __restrict__ bdfp,
    const float* __restrict__ wloc, const float* __restrict__ blocp,
    const float* __restrict__ wsc, const float* __restrict__ bscp,
    const float* __restrict__ h0f, const float* __restrict__ c0f,
    const float* __restrict__ h1f, const float* __restrict__ c1f,
    const float* __restrict__ ct, const float* __restrict__ RND,
    float* __restrict__ yhat, u32 kl0, u32 kl1)
{
  const int t     = threadIdx.x;
  const int lane  = t & 63;
  const int w     = t >> 6;        // wave 0..3
  const int r0    = w * 4;         // wave's first local row
  const int gbase = lane << 2;     // first gate of this lane's 4-gate group

  __shared__ __align__(16) float wbuf[2][4096];     // 32 KB weight chunk dbuf
  __shared__ __align__(16) float g_s[DROWS][256];   // 16 KB gate transpose
  __shared__ float hist[DROWS][64];                 // 4 KB lag ring
  __shared__ float h0b[DROWS][64];                  // 4 KB h0 broadcast
  __shared__ float h1b[DROWS][64];                  // 4 KB h1 broadcast
  __shared__ float xb[DROWS][16];                   // 1 KB x broadcast
  __shared__ float prevs[DROWS], tsr[DROWS];
  __shared__ float dfL[DROWS], locL[DROWS], scL[DROWS];

  const int base = blockIdx.x * DROWS;

  float c0reg[4], c1reg[4];
#pragma unroll
  for (int rr = 0; rr < 4; rr++) {
    const int bb = (base + r0 + rr) / NSAMP;
    h0b[r0 + rr][lane] = h0f[bb * 64 + lane];
    h1b[r0 + rr][lane] = h1f[bb * 64 + lane];
    c0reg[rr] = c0f[bb * 64 + lane];
    c1reg[rr] = c1f[bb * 64 + lane];
  }
  const float bs0 = bih0[lane]       + bhh0[lane];
  const float bs1 = bih0[64 + lane]  + bhh0[64 + lane];
  const float bs2 = bih0[128 + lane] + bhh0[128 + lane];
  const float bs3 = bih0[192 + lane] + bhh0[192 + lane];
  const float bs4 = bih1[lane]       + bhh1[lane];
  const float bs5 = bih1[64 + lane]  + bhh1[64 + lane];
  const float bs6 = bih1[128 + lane] + bhh1[128 + lane];
  const float bs7 = bih1[192 + lane] + bhh1[192 + lane];
  const float wdfv = wdf[lane], wlocv = wloc[lane], wscv = wsc[lane];
  const float bdf = bdfp[0], bloc = blocp[0], bsc = bscp[0];

  for (int idx = t; idx < DROWS * 28; idx += 256) {
    const int i = idx / 28, k = idx - i * 28;
    const int bb = (base + i) / NSAMP;
    hist[i][63 - k] = ct[bb * CTX + 335 - k];
  }
  if (t < DROWS) {
    const int rg = base + t;
    prevs[t] = yhat[(size_t)rg * TM1 + 335];
    tsr[t] = tscale[rg / NSAMP];
    xb[t][15] = 0.0f;                 // k=15 pad (weights there are 0 too)
  }
  stage16k(WPX, wbuf[0], w, lane);
  __syncthreads();                    // covers init LDS writes + prologue stage
  int buf = 0;

  for (int s = 0; s < NSTEP; s++) {
    // ---- build x vector for this wave's 4 rows ----
    if (lane < 15) {
#pragma unroll
      for (int rr = 0; rr < 4; rr++) {
        const int row = r0 + rr;
        float v;
        if (lane == 0) {
          v = prevs[row] / tsr[row];
          hist[row][s & 63] = v;
        } else if (lane <= 10) {
          v = hist[row][(s - c_LAGS[lane - 1]) & 63];
        } else {
          const int bb = (base + row) / NSAMP;
          v = inp[((size_t)bb * TM1 + CTX + s) * NIN + lane];
        }
        xb[row][lane] = v;
      }
    }

    v2f acc[4][4];
#pragma unroll
    for (int rr = 0; rr < 4; rr++) {
      acc[rr][0] = bc2(0.f); acc[rr][1] = bc2(0.f);
      acc[rr][2] = bc2(0.f); acc[rr][3] = bc2(0.f);
    }

    // ---- layer 0 gates: x part (chunk 0 = WPX) ----
    stage16k(WP00, wbuf[buf ^ 1], w, lane);
    chunk_mac(wbuf[buf], &xb[0][0], 16, 0, acc, r0, lane);
    __syncthreads(); buf ^= 1;

    // ---- layer 0 gates: h0_prev part (4 chunks of WP00) ----
#pragma unroll 1
    for (int q = 0; q < 4; q++) {
      const float* nsrc = (q < 3) ? (WP00 + (q + 1) * 4096) : WP10;
      stage16k(nsrc, wbuf[buf ^ 1], w, lane);
      chunk_mac(wbuf[buf], &h0b[0][0], 64, q * 8, acc, r0, lane);
      __syncthreads(); buf ^= 1;
    }

    // ---- cell 0 ----
#pragma unroll
    for (int rr = 0; rr < 4; rr++) {
      const int row = r0 + rr;
      float4 gv;
      gv.x = acc[rr][0][0] + acc[rr][0][1];
      gv.y = acc[rr][1][0] + acc[rr][1][1];
      gv.z = acc[rr][2][0] + acc[rr][2][1];
      gv.w = acc[rr][3][0] + acc[rr][3][1];
      *(float4*)&g_s[row][gbase] = gv;
    }
#pragma unroll
    for (int rr = 0; rr < 4; rr++) {
      const int row = r0 + rr;
      const float gi = g_s[row][lane]       + bs0;
      const float gf = g_s[row][64 + lane]  + bs1;
      const float gg = g_s[row][128 + lane] + bs2;
      const float go = g_s[row][192 + lane] + bs3;
      float c0 = c0reg[rr];
      c0 = sigm(gf) * c0 + sigm(gi) * tanhf(gg);
      c0reg[rr] = c0;
      h0b[row][lane] = sigm(go) * tanhf(c0);    // h0_new for phase B + next step
    }

#pragma unroll
    for (int rr = 0; rr < 4; rr++) {
      acc[rr][0] = bc2(0.f); acc[rr][1] = bc2(0.f);
      acc[rr][2] = bc2(0.f); acc[rr][3] = bc2(0.f);
    }

    // ---- layer 1 gates: h0_new part (4 chunks of WP10) ----
#pragma unroll 1
    for (int q = 0; q < 4; q++) {
      const float* nsrc = (q < 3) ? (WP10 + (q + 1) * 4096) : WP11;
      stage16k(nsrc, wbuf[buf ^ 1], w, lane);
      chunk_mac(wbuf[buf], &h0b[0][0], 64, q * 8, acc, r0, lane);
      __syncthreads(); buf ^= 1;
    }
    // ---- layer 1 gates: h1_prev part (4 chunks of WP11; last stages WPX) ----
#pragma unroll 1
    for (int q = 0; q < 4; q++) {
      const float* nsrc = (q < 3) ? (WP11 + (q + 1) * 4096) : WPX;
      stage16k(nsrc, wbuf[buf ^ 1], w, lane);
      chunk_mac(wbuf[buf], &h1b[0][0], 64, q * 8, acc, r0, lane);
      __syncthreads(); buf ^= 1;
    }

    // ---- cell 1 + head ----
#pragma unroll
    for (int rr = 0; rr < 4; rr++) {
      const int row = r0 + rr;
      float4 gv;
      gv.x = acc[rr][0][0] + acc[rr][0][1];
      gv.y = acc[rr][1][0] + acc[rr][1][1];
      gv.z = acc[rr][2][0] + acc[rr][2][1];
      gv.w = acc[rr][3][0] + acc[rr][3][1];
      *(float4*)&g_s[row][gbase] = gv;
    }
#pragma unroll
    for (int rr = 0; rr < 4; rr++) {
      const int row = r0 + rr;
      const float gi = g_s[row][lane]       + bs4;
      const float gf = g_s[row][64 + lane]  + bs5;
      const float gg = g_s[row][128 + lane] + bs6;
      const float go = g_s[row][192 + lane] + bs7;
      float c1 = c1reg[rr];
      c1 = sigm(gf) * c1 + sigm(gi) * tanhf(gg);
      c1reg[rr] = c1;
      const float h1v = sigm(go) * tanhf(c1);
      h1b[row][lane] = h1v;                     // for next step's phase B
      float pd = h1v * wdfv, pl = h1v * wlocv, ps = h1v * wscv;
#pragma unroll
      for (int off = 32; off > 0; off >>= 1) {
        pd += __shfl_down(pd, off, 64);
        pl += __shfl_down(pl, off, 64);
        ps += __shfl_down(ps, off, 64);
      }
      if (lane == 0) {
        dfL[row]  = 2.0f + softplusf(pd + bdf);
        locL[row] = pl + bloc;
        scL[row]  = softplusf(ps + bsc);
      }
    }

    // ---- sample (one lane per row) ----
    if (lane < 4) {
      const int row = r0 + lane, rg = base + row;
      const float dfv = dfL[row], lv = locL[row], scv = scL[row];
      const float* Rp = RND + ((size_t)s * RTOT + rg) * 4;
      const float z = Rp[0];
      const float alpha = dfv * 0.5f;
      float gam;
      {
#pragma clang fp contract(off)
        const float d = alpha - 0.33333334f;
        const float c = 0.33333334f / sqrtf(d);
        float x = Rp[1];
        float v = 1.0f + x * c;
        bool ok = true;
        if (v <= 0.0f) { x = Rp[2]; v = 1.0f + x * c; ok = (v > 0.0f); }
        const float X = x * x;
        const float V = (v * v) * v;
        const float U = Rp[3];
        bool accept = false;
        if (ok) {
          if (!(U >= 1.0f - 0.0331f * (X * X))) accept = true;
          else if (!(logf(U) >= 0.5f * X + d * ((1.0f - V) + logf(V)))) accept = true;
        }
        if (accept) {
          gam = d * V;
        } else {
          u32 ks0, ks1, skg0, skg1, gk0, gk1;
          tf2x32(kl0, kl1, 0u, (u32)s, ks0, ks1);
          tf2x32(ks0, ks1, 0u, 1u, skg0, skg1);
          jx_subkey(skg0, skg1, RTOT, (u32)rg, gk0, gk1);
          gam = jax_gamma_one(gk0, gk1, alpha);
        }
      }
      const float y = (lv + scv * (z * sqrtf(dfv / (2.0f * gam)))) * tsr[row];
      yhat[(size_t)rg * TM1 + CTX + s] = y;
      prevs[row] = y;
    }
  }
}

// ---------------- kernel 6: median over 100 samples per (b,t) ----------------
__global__ void __launch_bounds__(256) median_kernel(
    const float* __restrict__ yhat, float* __restrict__ out)
{
  __shared__ float vals[4][100];
  const int wave = threadIdx.x >> 6, lane = threadIdx.x & 63;
  const int cell = blockIdx.x * 4 + wave;
  const int b = cell / TM1, t = cell - b * TM1;
  const float* basep = yhat + (size_t)b * NSAMP * TM1 + t;
  const float v1 = basep[(size_t)lane * TM1];
  vals[wave][lane] = v1;
  float v2 = 0.f;
  if (lane < 36) { v2 = basep[(size_t)(64 + lane) * TM1]; vals[wave][64 + lane] = v2; }
  __syncthreads();
  int cl1 = 0, ce1 = 0, cl2 = 0, ce2 = 0;
  for (int jj = 0; jj < 100; jj++) {
    const float w = vals[wave][jj];
    cl1 += (w < v1); ce1 += (w == v1);
    cl2 += (w < v2); ce2 += (w == v2);
  }
  if (cl1 <= 49 && 49 < cl1 + ce1) out[cell] = v1;
  if (lane < 36 && cl2 <= 49 && 49 < cl2 + ce2) out[cell] = v2;
}

// ---------------- launch ----------------
extern "C" void kernel_launch(void* const* d_in, const int* in_sizes, int n_in,
                              void* d_out, int out_size, void* d_ws, size_t ws_size,
                              hipStream_t stream) {
  (void)in_sizes; (void)n_in; (void)out_size; (void)ws_size;
  const float* X     = (const float*)d_in[0];
  const float* Wih0  = (const float*)d_in[2];
  const float* Whh0  = (const float*)d_in[3];
  const float* bih0  = (const float*)d_in[4];
  const float* bhh0  = (const float*)d_in[5];
  const float* Wih1  = (const float*)d_in[6];
  const float* Whh1  = (const float*)d_in[7];
  const float* bih1  = (const float*)d_in[8];
  const float* bhh1  = (const float*)d_in[9];
  const float* wdf   = (const float*)d_in[10];
  const float* bdf   = (const float*)d_in[11];
  const float* wloc  = (const float*)d_in[12];
  const float* bloc  = (const float*)d_in[13];
  const float* wsc   = (const float*)d_in[14];
  const float* bsc   = (const float*)d_in[15];
  const float* emb   = (const float*)d_in[16];

  float* wsf = (float*)d_ws;
  float* inp  = wsf + OFF_INP;
  float* ct   = wsf + OFF_CT;
  float* ts   = wsf + OFF_TS;
  float* lts  = wsf + OFF_LTS;
  float* dfp  = wsf + OFF_DF;
  float* locp = wsf + OFF_LOC;
  float* scp  = wsf + OFF_SC;
  float* h0f  = wsf + OFF_H0F;
  float* c0f  = wsf + OFF_C0F;
  float* h1f  = wsf + OFF_H1F;
  float* c1f  = wsf + OFF_C1F;
  float* yhat = wsf + OFF_YH;
  float* wtx  = wsf + OFF_WTX;
  float* wt00 = wsf + OFF_WT00;
  float* wt10 = wsf + OFF_WT10;
  float* wt11 = wsf + OFF_WT11;
  float* wpx  = wsf + OFF_WPX;
  float* wp00 = wsf + OFF_WP00;
  float* wp10 = wsf + OFF_WP10;
  float* wp11 = wsf + OFF_WP11;
  float* rnd  = wsf + OFF_RND;

  const u32 key0 = 0u, key1 = 42u;
  u32 kc0, kc1, kl0, kl1;
  jx_subkey(key0, key1, 2u, 0u, kc0, kc1);
  jx_subkey(key0, key1, 2u, 1u, kl0, kl1);
  u32 kz0, kz1, kg0, kg1;
  jx_subkey(kc0, kc1, 2u, 0u, kz0, kz1);
  jx_subkey(kc0, kc1, 2u, 1u, kg0, kg1);

  wtrans_kernel<<<416, 256, 0, stream>>>(Wih0, Whh0, Wih1, Whh1,
                                         wtx, wt00, wt10, wt11,
                                         wpx, wp00, wp10, wp11);
  rnd_dec_kernel<<<(NSTEP * RTOT) / 256, 256, 0, stream>>>(rnd, kl0, kl1);
  prep_kernel<<<NB, 256, 0, stream>>>(X, emb, inp, ct, ts, lts);
  ctx_lstm_kernel<<<NB, 256, 0, stream>>>(inp, wtx, wt00, wt10, wt11,
                                          bih0, bhh0, bih1, bhh1,
                                          wdf, bdf, wloc, bloc, wsc, bsc,
                                          dfp, locp, scp, h0f, c0f, h1f, c1f);
  ctx_sample_kernel<<<NCTXS / 256, 256, 0, stream>>>(dfp, locp, scp, ts, yhat, kz0, kz1, kg0, kg1);
  dec_persist_kernel<<<DBLOCKS, 256, 0, stream>>>(inp, ts, wpx, wp00, wp10, wp11,
                                                  bih0, bhh0, bih1, bhh1,
                                                  wdf, bdf, wloc, bloc, wsc, bsc,
                                                  h0f, c0f, h1f, c1f, ct, rnd, yhat, kl0, kl1);
  median_kernel<<<(NB * TM1) / 4, 256, 0, stream>>>(yhat, (float*)d_out);
}

// Round 2
// 4824.711 us; speedup vs baseline: 1.1000x; 1.1000x over previous
//
#include <hip/hip_runtime.h>
#include <stdint.h>
#include <stddef.h>

typedef uint32_t u32;
typedef float v2f __attribute__((ext_vector_type(2)));
typedef _Float16 f16;
typedef f16 h2 __attribute__((ext_vector_type(2)));
typedef f16 h8 __attribute__((ext_vector_type(8)));

// ---------------- problem constants (fixed by reference file) ----------------
#define NB    256      // batch B
#define LFULL 412      // L
#define NCH   3        // C
#define CTX   336      // context_length
#define NSAMP 100      // n_samples
#define TM1   383      // T-1 (T = L - MAX_LAG = 384)
#define HID   64
#define NIN   15
#define RTOT  25600    // NB*NSAMP
#define NCTXS 8601600u // RTOT*CTX
#define NSTEP 47       // H-1

#define DROWS   32     // rows per persistent decode block (4 per wave, 8 waves)
#define DBLOCKS (RTOT / DROWS)  // 800

#define JAX_PARTITIONABLE 1

__device__ const int c_LAGS[10] = {1,2,3,4,5,6,7,14,21,28};

__device__ inline v2f bc2(float x) { v2f r; r[0] = x; r[1] = x; return r; }

// fp16 pair dot product with fp32 accumulate (v_dot2_f32_f16)
__device__ __forceinline__ float dot2(h2 a, h2 b, float c) {
#if __has_builtin(__builtin_amdgcn_fdot2)
  return __builtin_amdgcn_fdot2(a, b, c, false);
#else
  return c + (float)a[0] * (float)b[0] + (float)a[1] * (float)b[1];
#endif
}

// ---------------- threefry2x32 (matches jax._src.prng) ----------------
__host__ __device__ inline void tf2x32(u32 k0, u32 k1, u32 x0, u32 x1, u32& o0, u32& o1) {
  const u32 ks2 = k0 ^ k1 ^ 0x1BD11BDAu;
#define TFR(r) { x0 += x1; x1 = (x1 << (r)) | (x1 >> (32 - (r))); x1 ^= x0; }
  x0 += k0; x1 += k1;
  TFR(13) TFR(15) TFR(26) TFR(6)
  x0 += k1; x1 += ks2 + 1u;
  TFR(17) TFR(29) TFR(16) TFR(24)
  x0 += ks2; x1 += k0 + 2u;
  TFR(13) TFR(15) TFR(26) TFR(6)
  x0 += k0; x1 += k1 + 3u;
  TFR(17) TFR(29) TFR(16) TFR(24)
  x0 += k1; x1 += ks2 + 4u;
  TFR(13) TFR(15) TFR(26) TFR(6)
  x0 += ks2; x1 += k0 + 5u;
#undef TFR
  o0 = x0; o1 = x1;
}

__host__ __device__ inline u32 split_word_legacy(u32 k0, u32 k1, u32 n, u32 j) {
  u32 o0, o1;
  if (j < n) { tf2x32(k0, k1, j, n + j, o0, o1); return o0; }
  tf2x32(k0, k1, j - n, j, o0, o1); return o1;
}

__host__ __device__ inline void jx_subkey(u32 k0, u32 k1, u32 n, u32 i, u32& s0, u32& s1) {
#if JAX_PARTITIONABLE
  (void)n; tf2x32(k0, k1, 0u, i, s0, s1);
#else
  s0 = split_word_legacy(k0, k1, n, 2u * i);
  s1 = split_word_legacy(k0, k1, n, 2u * i + 1u);
#endif
}

__device__ inline u32 jx_bits(u32 k0, u32 k1, u32 n, u32 i) {
#if JAX_PARTITIONABLE
  (void)n; u32 o0, o1; tf2x32(k0, k1, 0u, i, o0, o1); return o0 ^ o1;
#else
  u32 o0, o1;
  if (n == 1u) { tf2x32(k0, k1, 0u, 0u, o0, o1); return o0; }
  const u32 h = n >> 1;
  if (i < h) { tf2x32(k0, k1, i, h + i, o0, o1); return o0; }
  tf2x32(k0, k1, i - h, i, o0, o1); return o1;
#endif
}

// ---------------- JAX-exact float transforms ----------------
__device__ inline float jax_erfinv(float x) {
#pragma clang fp contract(off)
  float w = -log1pf(-x * x);
  float p;
  if (w < 5.0f) {
    w = w - 2.5f;
    p = 2.81022636e-08f;
    p = 3.43273939e-07f + p * w;
    p = -3.5233877e-06f + p * w;
    p = -4.39150654e-06f + p * w;
    p = 0.00021858087f + p * w;
    p = -0.00125372503f + p * w;
    p = -0.00417768164f + p * w;
    p = 0.246640727f + p * w;
    p = 1.50140941f + p * w;
  } else {
    w = sqrtf(w) - 3.0f;
    p = -0.000200214257f;
    p = 0.000100950558f + p * w;
    p = 0.00134934322f + p * w;
    p = -0.00367342844f + p * w;
    p = 0.00573950773f + p * w;
    p = -0.0076224613f + p * w;
    p = 0.00943887047f + p * w;
    p = 1.00167406f + p * w;
    p = 2.83297682f + p * w;
  }
  return p * x;
}

__device__ inline float u01_from_bits(u32 bits) {
  return __uint_as_float((bits >> 9) | 0x3f800000u) - 1.0f;
}

__device__ inline float normal_from_bits(u32 bits) {
#pragma clang fp contract(off)
  const float lo = -0.99999994f;
  const float u = u01_from_bits(bits);
  float r = u * 2.0f + lo;
  r = fmaxf(lo, r);
  return 1.41421356f * jax_erfinv(r);
}

__device__ float jax_gamma_one(u32 k0, u32 k1, float alpha) {
#pragma clang fp contract(off)
  const bool boost_mask = (alpha >= 1.0f);
  const float alpha_orig = alpha;
  const float a = boost_mask ? alpha : (alpha + 1.0f);
  const float d = a - 0.33333334f;
  const float c = 0.33333334f / sqrtf(d);
  u32 K0, K1, S0, S1;
  jx_subkey(k0, k1, 2u, 0u, K0, K1);
  jx_subkey(k0, k1, 2u, 1u, S0, S1);
  float u_boost = 1.0f;
  if (!boost_mask) u_boost = u01_from_bits(jx_bits(S0, S1, 1u, 0u));
  float X = 0.0f, V = 1.0f, U = 2.0f;
  while (true) {
    if (!(U >= 1.0f - 0.0331f * (X * X))) break;
    if (!(logf(U) >= 0.5f * X + d * ((1.0f - V) + logf(V)))) break;
    u32 nk0, nk1, xk0, xk1, uk0, uk1;
    jx_subkey(K0, K1, 3u, 0u, nk0, nk1);
    jx_subkey(K0, K1, 3u, 1u, xk0, xk1);
    jx_subkey(K0, K1, 3u, 2u, uk0, uk1);
    K0 = nk0; K1 = nk1;
    float x, v;
    u32 c0 = xk0, c1 = xk1;
    do {
      u32 t0, t1, s0, s1;
      jx_subkey(c0, c1, 2u, 0u, t0, t1);
      jx_subkey(c0, c1, 2u, 1u, s0, s1);
      c0 = t0; c1 = t1;
      x = normal_from_bits(jx_bits(s0, s1, 1u, 0u));
      v = 1.0f + x * c;
    } while (v <= 0.0f);
    X = x * x;
    V = (v * v) * v;
    U = u01_from_bits(jx_bits(uk0, uk1, 1u, 0u));
  }
  const float sample = d * V;
  const float boost = boost_mask ? 1.0f : powf(u_boost, 1.0f / alpha_orig);
  return sample * boost;
}

__device__ inline float sigm(float x) { return 1.0f / (1.0f + expf(-x)); }
__device__ inline float softplusf(float x) { return fmaxf(x, 0.0f) + log1pf(expf(-fabsf(x))); }

// cross-lane broadcast on the VALU pipe (not DS): v_readlane -> SGPR (ctx kernel)
__device__ inline float rl_f(float v, int l) {
  return __int_as_float(__builtin_amdgcn_readlane(__float_as_int(v), l));
}

// ---------------- workspace layout (floats) ----------------
enum : size_t {
  OFF_INP  = 0,
  OFF_CT   = OFF_INP + (size_t)NB * TM1 * NIN,
  OFF_TS   = OFF_CT + (size_t)NB * CTX,
  OFF_LTS  = OFF_TS + NB,
  OFF_DF   = OFF_LTS + NB,
  OFF_LOC  = OFF_DF + (size_t)NB * CTX,
  OFF_SC   = OFF_LOC + (size_t)NB * CTX,
  OFF_H0F  = OFF_SC + (size_t)NB * CTX,
  OFF_C0F  = OFF_H0F + (size_t)NB * HID,
  OFF_H1F  = OFF_C0F + (size_t)NB * HID,
  OFF_C1F  = OFF_H1F + (size_t)NB * HID,
  OFF_YH   = OFF_C1F + (size_t)NB * HID,
  OFF_WTX  = OFF_YH + (size_t)RTOT * TM1,     // Wih0^T padded [16][256] (ctx kernel)
  OFF_WT00 = OFF_WTX + 4096,                  // Whh0^T [64][256]
  OFF_WT10 = OFF_WT00 + 16384,                // Wih1^T [64][256]
  OFF_WT11 = OFF_WT10 + 16384,                // Whh1^T [64][256]
  OFF_WH   = OFF_WT11 + 16384,                // fp16 kpair weights, 53248 halves = 26624 floats
  OFF_RND  = OFF_WH + 26624,                  // decode randoms [NSTEP][RTOT][4]
  WS_FLOATS = OFF_RND + (size_t)NSTEP * RTOT * 4
};

// fp16 weight blob segment offsets (in halves)
#define WH_X   0
#define WH_00  4096
#define WH_10  20480
#define WH_11  36864
#define WH_TOT 53248

// ---------------- kernel 0a: transpose weights (fp32, ctx kernel) -----------
__global__ void __launch_bounds__(256) wtrans_kernel(
    const float* __restrict__ Wih0, const float* __restrict__ Whh0,
    const float* __restrict__ Wih1, const float* __restrict__ Whh1,
    float* __restrict__ WTx, float* __restrict__ WT00,
    float* __restrict__ WT10, float* __restrict__ WT11)
{
  const int i = blockIdx.x * 256 + threadIdx.x;   // < 53248
  if (i < 4096) {
    const int k = i >> 8, g = i & 255;
    WTx[i] = (k < 15) ? Wih0[g * 15 + k] : 0.0f;
  } else if (i < 4096 + 16384) {
    const int j = i - 4096, k = j >> 8, g = j & 255;
    WT00[j] = Whh0[g * 64 + k];
  } else if (i < 4096 + 32768) {
    const int j = i - 4096 - 16384, k = j >> 8, g = j & 255;
    WT10[j] = Wih1[g * 64 + k];
  } else {
    const int j = i - 4096 - 32768, k = j >> 8, g = j & 255;
    WT11[j] = Whh1[g * 64 + k];
  }
}

// ---------------- kernel 0a2: fp16 kpair-interleaved weights for decode ------
// half index j (within segment): kp = j>>9; r = j&511; l = r>>3 (lane);
// g4 = (r>>1)&3; ke = r&1;  gate g = 4l+g4, k = 2kp+ke.
// Lane l's per-kpair 16B (8 halves) = {g0:(ke0,ke1), g1, g2, g3} -> one
// ds_read_b128 at 16B lane stride (conflict-free), 4x dot2 per row.
__global__ void __launch_bounds__(256) wh_kernel(
    const float* __restrict__ Wih0, const float* __restrict__ Whh0,
    const float* __restrict__ Wih1, const float* __restrict__ Whh1,
    f16* __restrict__ WH)
{
  const int j = blockIdx.x * 256 + threadIdx.x;   // < 53248
  int q, which;
  if (j < WH_00)      { q = j;         which = 0; }
  else if (j < WH_10) { q = j - WH_00; which = 1; }
  else if (j < WH_11) { q = j - WH_10; which = 2; }
  else                { q = j - WH_11; which = 3; }
  const int kp = q >> 9, r = q & 511;
  const int l = r >> 3, g4 = (r >> 1) & 3, ke = r & 1;
  const int g = l * 4 + g4, k = kp * 2 + ke;
  float v;
  if (which == 0)      v = (k < 15) ? Wih0[g * 15 + k] : 0.0f;
  else if (which == 1) v = Whh0[g * 64 + k];
  else if (which == 2) v = Wih1[g * 64 + k];
  else                 v = Whh1[g * 64 + k];
  WH[j] = (f16)v;
}

// ---------------- kernel 0b: precompute decode randoms -----------------------
__global__ void __launch_bounds__(256) rnd_dec_kernel(
    float* __restrict__ RND, u32 kl0, u32 kl1)
{
  const int i = blockIdx.x * 256 + threadIdx.x;   // < NSTEP*RTOT = 1203200
  const int s = i / RTOT, rg = i - s * RTOT;
  u32 ks0, ks1, skz0, skz1, skg0, skg1;
  tf2x32(kl0, kl1, 0u, (u32)s, ks0, ks1);
  tf2x32(ks0, ks1, 0u, 0u, skz0, skz1);
  tf2x32(ks0, ks1, 0u, 1u, skg0, skg1);
  const float z = normal_from_bits(jx_bits(skz0, skz1, RTOT, (u32)rg));
  u32 gk0, gk1;
  jx_subkey(skg0, skg1, RTOT, (u32)rg, gk0, gk1);
  u32 K0, K1, S0, S1;
  jx_subkey(gk0, gk1, 2u, 0u, K0, K1);
  jx_subkey(gk0, gk1, 2u, 1u, S0, S1);   // boost key, unused (alpha >= 1)
  u32 nk0, nk1, xk0, xk1, uk0, uk1;
  jx_subkey(K0, K1, 3u, 0u, nk0, nk1);
  jx_subkey(K0, K1, 3u, 1u, xk0, xk1);
  jx_subkey(K0, K1, 3u, 2u, uk0, uk1);
  u32 c0 = xk0, c1 = xk1, t0, t1, s0, s1;
  jx_subkey(c0, c1, 2u, 0u, t0, t1);
  jx_subkey(c0, c1, 2u, 1u, s0, s1);
  const float x1 = normal_from_bits(jx_bits(s0, s1, 1u, 0u));
  c0 = t0; c1 = t1;
  jx_subkey(c0, c1, 2u, 0u, t0, t1);
  jx_subkey(c0, c1, 2u, 1u, s0, s1);
  const float x2 = normal_from_bits(jx_bits(s0, s1, 1u, 0u));
  const float U1 = u01_from_bits(jx_bits(uk0, uk1, 1u, 0u));
  float* R = RND + (size_t)i * 4;
  R[0] = z; R[1] = x1; R[2] = x2; R[3] = U1;
}

// ---------------- kernel 1: tscale + feature build ----------------
__global__ void __launch_bounds__(256) prep_kernel(
    const float* __restrict__ X, const float* __restrict__ emb,
    float* __restrict__ inp, float* __restrict__ ct,
    float* __restrict__ tscale, float* __restrict__ ltscale)
{
  const int b = blockIdx.x, t = threadIdx.x;
  __shared__ float red[256];
  __shared__ float ts_sh;
  const float* Xb = X + (size_t)b * LFULL * NCH;
  float p = fabsf(Xb[(28 + t) * NCH]);
  if (t < 80) p += fabsf(Xb[(28 + 256 + t) * NCH]);
  red[t] = p;
  for (int st = 128; st > 0; st >>= 1) { __syncthreads(); if (t < st) red[t] += red[t + st]; }
  __syncthreads();
  if (t == 0) {
    float ts = red[0] / 336.0f;
    ts = fmaxf(ts, 1e-10f);
    tscale[b] = ts; ltscale[b] = logf(ts); ts_sh = ts;
  }
  __syncthreads();
  const float ts = ts_sh;
  const float lts = logf(ts);
  const float ev = emb[0];
  for (int idx = t; idx < TM1 * NIN; idx += 256) {
    const int tt = idx / NIN, f = idx - tt * NIN;
    float val;
    if (f == 0)       val = (tt < CTX) ? Xb[(28 + tt) * NCH] / ts : 0.0f;
    else if (f <= 10) val = (tt < CTX) ? Xb[(28 + tt - c_LAGS[f - 1]) * NCH] / ts : 0.0f;
    else if (f == 11) val = ev;
    else if (f == 12) val = Xb[(28 + tt) * NCH + 2];
    else if (f == 13) val = lts;
    else              val = Xb[(28 + tt) * NCH + 1];
    inp[(size_t)(b * TM1 + tt) * NIN + f] = val;
    if (f == 0 && tt < CTX) ct[b * CTX + tt] = val;
  }
}

// ---------------- kernel 2: context LSTM (unchanged, exact fp32) -------------
__global__ void __launch_bounds__(256) ctx_lstm_kernel(
    const float* __restrict__ inp,
    const float* __restrict__ WTx, const float* __restrict__ WT00,
    const float* __restrict__ WT10, const float* __restrict__ WT11,
    const float* __restrict__ bih0, const float* __restrict__ bhh0,
    const float* __restrict__ bih1, const float* __restrict__ bhh1,
    const float* __restrict__ wdf, const float* __restrict__ bdfp,
    const float* __restrict__ wloc, const float* __restrict__ blocp,
    const float* __restrict__ wsc, const float* __restrict__ bscp,
    float* __restrict__ dfo, float* __restrict__ loco, float* __restrict__ sco,
    float* __restrict__ h0f, float* __restrict__ c0f,
    float* __restrict__ h1f, float* __restrict__ c1f)
{
  const int b = blockIdx.x, t = threadIdx.x;
  const int lane = t & 63, w = t >> 6;
  const int gbase = lane << 2;
  __shared__ __align__(16) float gA[4][256];
  __shared__ __align__(16) float gB[4][256];

  const float bs0 = bih0[lane]       + bhh0[lane];
  const float bs1 = bih0[64 + lane]  + bhh0[64 + lane];
  const float bs2 = bih0[128 + lane] + bhh0[128 + lane];
  const float bs3 = bih0[192 + lane] + bhh0[192 + lane];
  const float bs4 = bih1[lane]       + bhh1[lane];
  const float bs5 = bih1[64 + lane]  + bhh1[64 + lane];
  const float bs6 = bih1[128 + lane] + bhh1[128 + lane];
  const float bs7 = bih1[192 + lane] + bhh1[192 + lane];
  const float wdfv = wdf[lane], wlocv = wloc[lane], wscv = wsc[lane];
  const float bdf = bdfp[0], bloc = blocp[0], bsc = bscp[0];

  float h0r = 0.f, h1r = 0.f, c0r = 0.f, c1r = 0.f;
  const float* inb = inp + (size_t)b * TM1 * NIN;
  const int kx = w * 4;    // x-part k-quarter
  const int kh = w * 16;   // h-part k-quarter

  for (int tt = 0; tt < CTX; tt++) {
    float xr = 0.f;
    if (lane < 15) xr = inb[tt * NIN + lane];

    v2f aA = bc2(0.0f), aB = bc2(0.0f);
#pragma unroll
    for (int kk = 0; kk < 4; kk++) {
      const int k = kx + kk;
      const float4 wv = *(const float4*)&WTx[(k << 8) + gbase];
      v2f wlo, whi; wlo[0] = wv.x; wlo[1] = wv.y; whi[0] = wv.z; whi[1] = wv.w;
      const v2f hk = bc2(rl_f(xr, k));
      aA += wlo * hk; aB += whi * hk;
    }
#pragma unroll
    for (int kk = 0; kk < 16; kk++) {
      const int k = kh + kk;
      const float4 wv = *(const float4*)&WT00[(k << 8) + gbase];
      v2f wlo, whi; wlo[0] = wv.x; wlo[1] = wv.y; whi[0] = wv.z; whi[1] = wv.w;
      const v2f hk = bc2(rl_f(h0r, k));
      aA += wlo * hk; aB += whi * hk;
    }
    {
      float4 gv; gv.x = aA[0]; gv.y = aA[1]; gv.z = aB[0]; gv.w = aB[1];
      *(float4*)&gA[w][gbase] = gv;
    }
    __syncthreads();

    {
      float gi = ((gA[0][lane]       + gA[1][lane])       + gA[2][lane])       + gA[3][lane];
      float gf = ((gA[0][64 + lane]  + gA[1][64 + lane])  + gA[2][64 + lane])  + gA[3][64 + lane];
      float gg = ((gA[0][128 + lane] + gA[1][128 + lane]) + gA[2][128 + lane]) + gA[3][128 + lane];
      float go = ((gA[0][192 + lane] + gA[1][192 + lane]) + gA[2][192 + lane]) + gA[3][192 + lane];
      gi += bs0; gf += bs1; gg += bs2; go += bs3;
      c0r = sigm(gf) * c0r + sigm(gi) * tanhf(gg);
      h0r = sigm(go) * tanhf(c0r);
    }

    aA = bc2(0.0f); aB = bc2(0.0f);
#pragma unroll
    for (int kk = 0; kk < 16; kk++) {
      const int k = kh + kk;
      const float4 wv = *(const float4*)&WT10[(k << 8) + gbase];
      v2f wlo, whi; wlo[0] = wv.x; wlo[1] = wv.y; whi[0] = wv.z; whi[1] = wv.w;
      const v2f hk = bc2(rl_f(h0r, k));
      aA += wlo * hk; aB += whi * hk;
    }
#pragma unroll
    for (int kk = 0; kk < 16; kk++) {
      const int k = kh + kk;
      const float4 wv = *(const float4*)&WT11[(k << 8) + gbase];
      v2f wlo, whi; wlo[0] = wv.x; wlo[1] = wv.y; whi[0] = wv.z; whi[1] = wv.w;
      const v2f hk = bc2(rl_f(h1r, k));
      aA += wlo * hk; aB += whi * hk;
    }
    {
      float4 gv; gv.x = aA[0]; gv.y = aA[1]; gv.z = aB[0]; gv.w = aB[1];
      *(float4*)&gB[w][gbase] = gv;
    }
    __syncthreads();

    {
      float gi = ((gB[0][lane]       + gB[1][lane])       + gB[2][lane])       + gB[3][lane];
      float gf = ((gB[0][64 + lane]  + gB[1][64 + lane])  + gB[2][64 + lane])  + gB[3][64 + lane];
      float gg = ((gB[0][128 + lane] + gB[1][128 + lane]) + gB[2][128 + lane]) + gB[3][128 + lane];
      float go = ((gB[0][192 + lane] + gB[1][192 + lane]) + gB[2][192 + lane]) + gB[3][192 + lane];
      gi += bs4; gf += bs5; gg += bs6; go += bs7;
      c1r = sigm(gf) * c1r + sigm(gi) * tanhf(gg);
      h1r = sigm(go) * tanhf(c1r);
      if (w == 0) {
        float pd = h1r * wdfv, pl = h1r * wlocv, ps = h1r * wscv;
#pragma unroll
        for (int off = 32; off > 0; off >>= 1) {
          pd += __shfl_down(pd, off, 64);
          pl += __shfl_down(pl, off, 64);
          ps += __shfl_down(ps, off, 64);
        }
        if (lane == 0) {
          dfo[b * CTX + tt]  = 2.0f + softplusf(pd + bdf);
          loco[b * CTX + tt] = pl + bloc;
          sco[b * CTX + tt]  = softplusf(ps + bsc);
        }
      }
    }
  }
  if (w == 0) {
    h0f[b * 64 + lane] = h0r; c0f[b * 64 + lane] = c0r;
    h1f[b * 64 + lane] = h1r; c1f[b * 64 + lane] = c1r;
  }
}

// ---------------- kernel 3: context sampling (y_ctx) ----------------
__global__ void __launch_bounds__(256) ctx_sample_kernel(
    const float* __restrict__ df, const float* __restrict__ loc, const float* __restrict__ sc,
    const float* __restrict__ tscale, float* __restrict__ yhat,
    u32 kz0, u32 kz1, u32 kg0, u32 kg1)
{
  const int i = blockIdx.x * 256 + threadIdx.x;
  const int r = i / CTX, t = i - r * CTX;
  const int b = r / NSAMP;
  const float dfv = df[b * CTX + t], lv = loc[b * CTX + t], sv = sc[b * CTX + t];
  const float z = normal_from_bits(jx_bits(kz0, kz1, NCTXS, (u32)i));
  u32 gk0, gk1;
  jx_subkey(kg0, kg1, NCTXS, (u32)i, gk0, gk1);
  const float g = jax_gamma_one(gk0, gk1, dfv * 0.5f);
  const float y = (lv + sv * (z * sqrtf(dfv / (2.0f * g)))) * tscale[b];
  yhat[(size_t)r * TM1 + t] = y;
}

// ---------------- decode MAC helper ------------------------------------------
// NKP kpairs from LDS fp16 weights; 4 rows; acc[row][g4] fp32 via v_dot2_f32_f16.
template <int NKP>
__device__ __forceinline__ void mac_seg(const f16* __restrict__ wseg,
                                        const f16* __restrict__ hbase,
                                        const int hstride, float (&acc)[4][4],
                                        const int r0, const int lane)
{
#pragma unroll 4
  for (int kp = 0; kp < NKP; kp++) {
    const h8 wv = *(const h8*)&wseg[(kp << 9) + (lane << 3)];
    h2 w0, w1, w2, w3;
    w0[0] = wv[0]; w0[1] = wv[1];
    w1[0] = wv[2]; w1[1] = wv[3];
    w2[0] = wv[4]; w2[1] = wv[5];
    w3[0] = wv[6]; w3[1] = wv[7];
#pragma unroll
    for (int rr = 0; rr < 4; rr++) {
      const h2 hp = *(const h2*)&hbase[(r0 + rr) * hstride + (kp << 1)];
      acc[rr][0] = dot2(w0, hp, acc[rr][0]);
      acc[rr][1] = dot2(w1, hp, acc[rr][1]);
      acc[rr][2] = dot2(w2, hp, acc[rr][2]);
      acc[rr][3] = dot2(w3, hp, acc[rr][3]);
    }
  }
}

// ---------------- kernel 5: persistent decode (fp16 LDS-resident weights) ----
// R1: all 104KB of fp16 weights live in LDS for the whole 47-step loop (staged
// once via global_load_lds + ONE barrier).  8 waves x 4 rows; all mutable LDS
// is wave-private rows => zero in-loop barriers (R0's 13 barrier-drains were
// the regression).  MACs are v_dot2_f32_f16 (2 MAC/inst, fp32 accum); h/x
// broadcasts are uniform-address ds_read_b32 (DS pipe, off VALU).
__global__ void __launch_bounds__(512) dec_persist_kernel(
    const float* __restrict__ inp, const float* __restrict__ tscale,
    const f16* __restrict__ WH,
    const float* __restrict__ bih0, const float* __restrict__ bhh0,
    const float* __restrict__ bih1, const float* __restrict__ bhh1,
    const float* __restrict__ wdf, const float* __restrict__ bdfp,
    const float* __restrict__ wloc, const float* __restrict__ blocp,
    const float* __restrict__ wsc, const float* __restrict__ bscp,
    const float* __restrict__ h0f, const float* __restrict__ c0f,
    const float* __restrict__ h1f, const float* __restrict__ c1f,
    const float* __restrict__ ct, const float* __restrict__ RND,
    float* __restrict__ yhat, u32 kl0, u32 kl1)
{
  const int t     = threadIdx.x;
  const int lane  = t & 63;
  const int w     = t >> 6;        // wave 0..7
  const int r0    = w * 4;         // wave's first local row
  const int gbase = lane << 2;

  __shared__ __align__(16) f16   wgt[WH_TOT];       // 104 KB fp16 weights
  __shared__ __align__(16) float g_s[DROWS][256];   // 32 KB gate transpose
  __shared__ __align__(16) f16   h0h[DROWS][64];    // 4 KB
  __shared__ __align__(16) f16   h1h[DROWS][64];    // 4 KB
  __shared__ __align__(16) f16   xh[DROWS][16];     // 1 KB
  __shared__ __align__(16) f16   hist[DROWS][32];   // 2 KB lag ring
  __shared__ __align__(16) f16   fst[2][NSTEP][4];  // 752 B feature stash
  __shared__ float prevs[DROWS], tsr[DROWS];
  __shared__ float dfL[DROWS], locL[DROWS], scL[DROWS];
  __shared__ unsigned char rsel[DROWS];

  const int base = blockIdx.x * DROWS;
  const int bblo = base / NSAMP;

  // ---- stage all weights: 13 x (8 waves x 64 lanes x 16B) = 106496 B ----
#pragma unroll
  for (int i = 0; i < 13; i++) {
    const int off = (i * 8 + w) * 512;   // halves
    __builtin_amdgcn_global_load_lds(
        (const __attribute__((address_space(1))) void*)(WH + off + lane * 8),
        (__attribute__((address_space(3))) void*)(wgt + off), 16, 0, 0);
  }

  float c0reg[4], c1reg[4];
#pragma unroll
  for (int rr = 0; rr < 4; rr++) {
    const int bb = (base + r0 + rr) / NSAMP;
    h0h[r0 + rr][lane] = (f16)h0f[bb * 64 + lane];
    h1h[r0 + rr][lane] = (f16)h1f[bb * 64 + lane];
    c0reg[rr] = c0f[bb * 64 + lane];
    c1reg[rr] = c1f[bb * 64 + lane];
  }
  const float bs0 = bih0[lane]       + bhh0[lane];
  const float bs1 = bih0[64 + lane]  + bhh0[64 + lane];
  const float bs2 = bih0[128 + lane] + bhh0[128 + lane];
  const float bs3 = bih0[192 + lane] + bhh0[192 + lane];
  const float bs4 = bih1[lane]       + bhh1[lane];
  const float bs5 = bih1[64 + lane]  + bhh1[64 + lane];
  const float bs6 = bih1[128 + lane] + bhh1[128 + lane];
  const float bs7 = bih1[192 + lane] + bhh1[192 + lane];
  const float wdfv = wdf[lane], wlocv = wloc[lane], wscv = wsc[lane];
  const float bdf = bdfp[0], bloc = blocp[0], bsc = bscp[0];

  for (int idx = t; idx < DROWS * 28; idx += 512) {
    const int i = idx / 28, k = idx - i * 28;
    const int bb = (base + i) / NSAMP;
    hist[i][31 - k] = (f16)ct[bb * CTX + 335 - k];
  }
  // feature stash: rows of a block span at most 2 batch indices
  {
    const int bbhi = (base + DROWS - 1) / NSAMP;
    for (int idx = t; idx < 2 * NSTEP * 4; idx += 512) {
      const int sel = idx / (NSTEP * 4), rem = idx - sel * (NSTEP * 4);
      const int s = rem >> 2, f = rem & 3;
      const int bb = sel ? bbhi : bblo;
      fst[sel][s][f] = (f16)inp[((size_t)bb * TM1 + CTX + s) * NIN + 11 + f];
    }
  }
  if (t < DROWS) {
    const int rg = base + t;
    prevs[t] = yhat[(size_t)rg * TM1 + 335];
    tsr[t] = tscale[rg / NSAMP];
    xh[t][15] = (f16)0.0f;            // pad slot (weights there are 0 too)
    rsel[t] = (unsigned char)(((base + t) / NSAMP) != bblo);
  }
  __syncthreads();   // covers weight staging (vmcnt drain) + all init writes

  for (int s = 0; s < NSTEP; s++) {
    // ---- build x vector (fp16) for this wave's 4 rows ----
    if (lane < 15) {
#pragma unroll
      for (int rr = 0; rr < 4; rr++) {
        const int row = r0 + rr;
        f16 v;
        if (lane == 0) {
          const float nv = prevs[row] / tsr[row];
          v = (f16)nv;
          hist[row][s & 31] = v;
        } else if (lane <= 10) {
          v = hist[row][(s - c_LAGS[lane - 1]) & 31];
        } else {
          v = fst[rsel[row]][s][lane - 11];
        }
        xh[row][lane] = v;
      }
    }

    float acc[4][4];
#pragma unroll
    for (int rr = 0; rr < 4; rr++) {
      acc[rr][0] = 0.f; acc[rr][1] = 0.f; acc[rr][2] = 0.f; acc[rr][3] = 0.f;
    }

    // ---- layer 0 gates: x part + h0_prev part ----
    mac_seg<8>(wgt + WH_X, &xh[0][0], 16, acc, r0, lane);
    mac_seg<32>(wgt + WH_00, &h0h[0][0], 64, acc, r0, lane);

    // ---- cell 0 ----
#pragma unroll
    for (int rr = 0; rr < 4; rr++) {
      const int row = r0 + rr;
      float4 gv; gv.x = acc[rr][0]; gv.y = acc[rr][1]; gv.z = acc[rr][2]; gv.w = acc[rr][3];
      *(float4*)&g_s[row][gbase] = gv;
    }
#pragma unroll
    for (int rr = 0; rr < 4; rr++) {
      const int row = r0 + rr;
      const float gi = g_s[row][lane]       + bs0;
      const float gf = g_s[row][64 + lane]  + bs1;
      const float gg = g_s[row][128 + lane] + bs2;
      const float go = g_s[row][192 + lane] + bs3;
      float c0 = c0reg[rr];
      c0 = sigm(gf) * c0 + sigm(gi) * tanhf(gg);
      c0reg[rr] = c0;
      h0h[row][lane] = (f16)(sigm(go) * tanhf(c0));   // h0_new for layer 1
    }

#pragma unroll
    for (int rr = 0; rr < 4; rr++) {
      acc[rr][0] = 0.f; acc[rr][1] = 0.f; acc[rr][2] = 0.f; acc[rr][3] = 0.f;
    }

    // ---- layer 1 gates: h0_new part + h1_prev part ----
    mac_seg<32>(wgt + WH_10, &h0h[0][0], 64, acc, r0, lane);
    mac_seg<32>(wgt + WH_11, &h1h[0][0], 64, acc, r0, lane);

    // ---- cell 1 + head ----
#pragma unroll
    for (int rr = 0; rr < 4; rr++) {
      const int row = r0 + rr;
      float4 gv; gv.x = acc[rr][0]; gv.y = acc[rr][1]; gv.z = acc[rr][2]; gv.w = acc[rr][3];
      *(float4*)&g_s[row][gbase] = gv;
    }
#pragma unroll
    for (int rr = 0; rr < 4; rr++) {
      const int row = r0 + rr;
      const float gi = g_s[row][lane]       + bs4;
      const float gf = g_s[row][64 + lane]  + bs5;
      const float gg = g_s[row][128 + lane] + bs6;
      const float go = g_s[row][192 + lane] + bs7;
      float c1 = c1reg[rr];
      c1 = sigm(gf) * c1 + sigm(gi) * tanhf(gg);
      c1reg[rr] = c1;
      const float h1v = sigm(go) * tanhf(c1);
      h1h[row][lane] = (f16)h1v;                 // for next step's layer 1
      float pd = h1v * wdfv, pl = h1v * wlocv, ps = h1v * wscv;
#pragma unroll
      for (int off = 32; off > 0; off >>= 1) {
        pd += __shfl_down(pd, off, 64);
        pl += __shfl_down(pl, off, 64);
        ps += __shfl_down(ps, off, 64);
      }
      if (lane == 0) {
        dfL[row]  = 2.0f + softplusf(pd + bdf);
        locL[row] = pl + bloc;
        scL[row]  = softplusf(ps + bsc);
      }
    }

    // ---- sample (one lane per row) ----
    if (lane < 4) {
      const int row = r0 + lane, rg = base + row;
      const float dfv = dfL[row], lv = locL[row], scv = scL[row];
      const float* Rp = RND + ((size_t)s * RTOT + rg) * 4;
      const float z = Rp[0];
      const float alpha = dfv * 0.5f;
      float gam;
      {
#pragma clang fp contract(off)
        const float d = alpha - 0.33333334f;
        const float c = 0.33333334f / sqrtf(d);
        float x = Rp[1];
        float v = 1.0f + x * c;
        bool ok = true;
        if (v <= 0.0f) { x = Rp[2]; v = 1.0f + x * c; ok = (v > 0.0f); }
        const float X = x * x;
        const float V = (v * v) * v;
        const float U = Rp[3];
        bool accept = false;
        if (ok) {
          if (!(U >= 1.0f - 0.0331f * (X * X))) accept = true;
          else if (!(logf(U) >= 0.5f * X + d * ((1.0f - V) + logf(V)))) accept = true;
        }
        if (accept) {
          gam = d * V;
        } else {
          u32 ks0, ks1, skg0, skg1, gk0, gk1;
          tf2x32(kl0, kl1, 0u, (u32)s, ks0, ks1);
          tf2x32(ks0, ks1, 0u, 1u, skg0, skg1);
          jx_subkey(skg0, skg1, RTOT, (u32)rg, gk0, gk1);
          gam = jax_gamma_one(gk0, gk1, alpha);
        }
      }
      const float y = (lv + scv * (z * sqrtf(dfv / (2.0f * gam)))) * tsr[row];
      yhat[(size_t)rg * TM1 + CTX + s] = y;
      prevs[row] = y;
    }
  }
}

// ---------------- kernel 6: median over 100 samples per (b,t) ----------------
__global__ void __launch_bounds__(256) median_kernel(
    const float* __restrict__ yhat, float* __restrict__ out)
{
  __shared__ float vals[4][100];
  const int wave = threadIdx.x >> 6, lane = threadIdx.x & 63;
  const int cell = blockIdx.x * 4 + wave;
  const int b = cell / TM1, t = cell - b * TM1;
  const float* basep = yhat + (size_t)b * NSAMP * TM1 + t;
  const float v1 = basep[(size_t)lane * TM1];
  vals[wave][lane] = v1;
  float v2 = 0.f;
  if (lane < 36) { v2 = basep[(size_t)(64 + lane) * TM1]; vals[wave][64 + lane] = v2; }
  __syncthreads();
  int cl1 = 0, ce1 = 0, cl2 = 0, ce2 = 0;
  for (int jj = 0; jj < 100; jj++) {
    const float w = vals[wave][jj];
    cl1 += (w < v1); ce1 += (w == v1);
    cl2 += (w < v2); ce2 += (w == v2);
  }
  if (cl1 <= 49 && 49 < cl1 + ce1) out[cell] = v1;
  if (lane < 36 && cl2 <= 49 && 49 < cl2 + ce2) out[cell] = v2;
}

// ---------------- launch ----------------
extern "C" void kernel_launch(void* const* d_in, const int* in_sizes, int n_in,
                              void* d_out, int out_size, void* d_ws, size_t ws_size,
                              hipStream_t stream) {
  (void)in_sizes; (void)n_in; (void)out_size; (void)ws_size;
  const float* X     = (const float*)d_in[0];
  const float* Wih0  = (const float*)d_in[2];
  const float* Whh0  = (const float*)d_in[3];
  const float* bih0  = (const float*)d_in[4];
  const float* bhh0  = (const float*)d_in[5];
  const float* Wih1  = (const float*)d_in[6];
  const float* Whh1  = (const float*)d_in[7];
  const float* bih1  = (const float*)d_in[8];
  const float* bhh1  = (const float*)d_in[9];
  const float* wdf   = (const float*)d_in[10];
  const float* bdf   = (const float*)d_in[11];
  const float* wloc  = (const float*)d_in[12];
  const float* bloc  = (const float*)d_in[13];
  const float* wsc   = (const float*)d_in[14];
  const float* bsc   = (const float*)d_in[15];
  const float* emb   = (const float*)d_in[16];

  float* wsf = (float*)d_ws;
  float* inp  = wsf + OFF_INP;
  float* ct   = wsf + OFF_CT;
  float* ts   = wsf + OFF_TS;
  float* lts  = wsf + OFF_LTS;
  float* dfp  = wsf + OFF_DF;
  float* locp = wsf + OFF_LOC;
  float* scp  = wsf + OFF_SC;
  float* h0f  = wsf + OFF_H0F;
  float* c0f  = wsf + OFF_C0F;
  float* h1f  = wsf + OFF_H1F;
  float* c1f  = wsf + OFF_C1F;
  float* yhat = wsf + OFF_YH;
  float* wtx  = wsf + OFF_WTX;
  float* wt00 = wsf + OFF_WT00;
  float* wt10 = wsf + OFF_WT10;
  float* wt11 = wsf + OFF_WT11;
  f16*   wh   = (f16*)(wsf + OFF_WH);
  float* rnd  = wsf + OFF_RND;

  const u32 key0 = 0u, key1 = 42u;
  u32 kc0, kc1, kl0, kl1;
  jx_subkey(key0, key1, 2u, 0u, kc0, kc1);
  jx_subkey(key0, key1, 2u, 1u, kl0, kl1);
  u32 kz0, kz1, kg0, kg1;
  jx_subkey(kc0, kc1, 2u, 0u, kz0, kz1);
  jx_subkey(kc0, kc1, 2u, 1u, kg0, kg1);

  wtrans_kernel<<<208, 256, 0, stream>>>(Wih0, Whh0, Wih1, Whh1, wtx, wt00, wt10, wt11);
  wh_kernel<<<208, 256, 0, stream>>>(Wih0, Whh0, Wih1, Whh1, wh);
  rnd_dec_kernel<<<(NSTEP * RTOT) / 256, 256, 0, stream>>>(rnd, kl0, kl1);
  prep_kernel<<<NB, 256, 0, stream>>>(X, emb, inp, ct, ts, lts);
  ctx_lstm_kernel<<<NB, 256, 0, stream>>>(inp, wtx, wt00, wt10, wt11,
                                          bih0, bhh0, bih1, bhh1,
                                          wdf, bdf, wloc, bloc, wsc, bsc,
                                          dfp, locp, scp, h0f, c0f, h1f, c1f);
  ctx_sample_kernel<<<NCTXS / 256, 256, 0, stream>>>(dfp, locp, scp, ts, yhat, kz0, kz1, kg0, kg1);
  dec_persist_kernel<<<DBLOCKS, 512, 0, stream>>>(inp, ts, wh,
                                                  bih0, bhh0, bih1, bhh1,
                                                  wdf, bdf, wloc, bloc, wsc, bsc,
                                                  h0f, c0f, h1f, c1f, ct, rnd, yhat, kl0, kl1);
  median_kernel<<<(NB * TM1) / 4, 256, 0, stream>>>(yhat, (float*)d_out);
}

// Round 3
// 4687.913 us; speedup vs baseline: 1.1321x; 1.0292x over previous
//
#include <hip/hip_runtime.h>
#include <stdint.h>
#include <stddef.h>

typedef uint32_t u32;
typedef float v2f __attribute__((ext_vector_type(2)));
typedef _Float16 f16;
typedef f16 h2 __attribute__((ext_vector_type(2)));
typedef f16 h8 __attribute__((ext_vector_type(8)));

// ---------------- problem constants (fixed by reference file) ----------------
#define NB    256      // batch B
#define LFULL 412      // L
#define NCH   3        // C
#define CTX   336      // context_length
#define NSAMP 100      // n_samples
#define TM1   383      // T-1 (T = L - MAX_LAG = 384)
#define HID   64
#define NIN   15
#define RTOT  25600    // NB*NSAMP
#define NCTXS 8601600u // RTOT*CTX
#define NSTEP 47       // H-1

#define DROWS   128    // rows per persistent decode block (16 per wave, 8 waves)
#define RPW     16     // rows per wave
#define DBLOCKS (RTOT / DROWS)  // 200  -> exactly <=1 block/CU, 1 round

#define JAX_PARTITIONABLE 1

__device__ const int c_LAGS[10] = {1,2,3,4,5,6,7,14,21,28};

__device__ inline v2f bc2(float x) { v2f r; r[0] = x; r[1] = x; return r; }

// fp16 pair dot product with fp32 accumulate (v_dot2_f32_f16)
__device__ __forceinline__ float dot2(h2 a, h2 b, float c) {
#if __has_builtin(__builtin_amdgcn_fdot2)
  return __builtin_amdgcn_fdot2(a, b, c, false);
#else
  return c + (float)a[0] * (float)b[0] + (float)a[1] * (float)b[1];
#endif
}

// ---------------- threefry2x32 (matches jax._src.prng) ----------------
__host__ __device__ inline void tf2x32(u32 k0, u32 k1, u32 x0, u32 x1, u32& o0, u32& o1) {
  const u32 ks2 = k0 ^ k1 ^ 0x1BD11BDAu;
#define TFR(r) { x0 += x1; x1 = (x1 << (r)) | (x1 >> (32 - (r))); x1 ^= x0; }
  x0 += k0; x1 += k1;
  TFR(13) TFR(15) TFR(26) TFR(6)
  x0 += k1; x1 += ks2 + 1u;
  TFR(17) TFR(29) TFR(16) TFR(24)
  x0 += ks2; x1 += k0 + 2u;
  TFR(13) TFR(15) TFR(26) TFR(6)
  x0 += k0; x1 += k1 + 3u;
  TFR(17) TFR(29) TFR(16) TFR(24)
  x0 += k1; x1 += ks2 + 4u;
  TFR(13) TFR(15) TFR(26) TFR(6)
  x0 += ks2; x1 += k0 + 5u;
#undef TFR
  o0 = x0; o1 = x1;
}

__host__ __device__ inline u32 split_word_legacy(u32 k0, u32 k1, u32 n, u32 j) {
  u32 o0, o1;
  if (j < n) { tf2x32(k0, k1, j, n + j, o0, o1); return o0; }
  tf2x32(k0, k1, j - n, j, o0, o1); return o1;
}

__host__ __device__ inline void jx_subkey(u32 k0, u32 k1, u32 n, u32 i, u32& s0, u32& s1) {
#if JAX_PARTITIONABLE
  (void)n; tf2x32(k0, k1, 0u, i, s0, s1);
#else
  s0 = split_word_legacy(k0, k1, n, 2u * i);
  s1 = split_word_legacy(k0, k1, n, 2u * i + 1u);
#endif
}

__device__ inline u32 jx_bits(u32 k0, u32 k1, u32 n, u32 i) {
#if JAX_PARTITIONABLE
  (void)n; u32 o0, o1; tf2x32(k0, k1, 0u, i, o0, o1); return o0 ^ o1;
#else
  u32 o0, o1;
  if (n == 1u) { tf2x32(k0, k1, 0u, 0u, o0, o1); return o0; }
  const u32 h = n >> 1;
  if (i < h) { tf2x32(k0, k1, i, h + i, o0, o1); return o0; }
  tf2x32(k0, k1, i - h, i, o0, o1); return o1;
#endif
}

// ---------------- JAX-exact float transforms ----------------
__device__ inline float jax_erfinv(float x) {
#pragma clang fp contract(off)
  float w = -log1pf(-x * x);
  float p;
  if (w < 5.0f) {
    w = w - 2.5f;
    p = 2.81022636e-08f;
    p = 3.43273939e-07f + p * w;
    p = -3.5233877e-06f + p * w;
    p = -4.39150654e-06f + p * w;
    p = 0.00021858087f + p * w;
    p = -0.00125372503f + p * w;
    p = -0.00417768164f + p * w;
    p = 0.246640727f + p * w;
    p = 1.50140941f + p * w;
  } else {
    w = sqrtf(w) - 3.0f;
    p = -0.000200214257f;
    p = 0.000100950558f + p * w;
    p = 0.00134934322f + p * w;
    p = -0.00367342844f + p * w;
    p = 0.00573950773f + p * w;
    p = -0.0076224613f + p * w;
    p = 0.00943887047f + p * w;
    p = 1.00167406f + p * w;
    p = 2.83297682f + p * w;
  }
  return p * x;
}

__device__ inline float u01_from_bits(u32 bits) {
  return __uint_as_float((bits >> 9) | 0x3f800000u) - 1.0f;
}

__device__ inline float normal_from_bits(u32 bits) {
#pragma clang fp contract(off)
  const float lo = -0.99999994f;
  const float u = u01_from_bits(bits);
  float r = u * 2.0f + lo;
  r = fmaxf(lo, r);
  return 1.41421356f * jax_erfinv(r);
}

__device__ float jax_gamma_one(u32 k0, u32 k1, float alpha) {
#pragma clang fp contract(off)
  const bool boost_mask = (alpha >= 1.0f);
  const float alpha_orig = alpha;
  const float a = boost_mask ? alpha : (alpha + 1.0f);
  const float d = a - 0.33333334f;
  const float c = 0.33333334f / sqrtf(d);
  u32 K0, K1, S0, S1;
  jx_subkey(k0, k1, 2u, 0u, K0, K1);
  jx_subkey(k0, k1, 2u, 1u, S0, S1);
  float u_boost = 1.0f;
  if (!boost_mask) u_boost = u01_from_bits(jx_bits(S0, S1, 1u, 0u));
  float X = 0.0f, V = 1.0f, U = 2.0f;
  while (true) {
    if (!(U >= 1.0f - 0.0331f * (X * X))) break;
    if (!(logf(U) >= 0.5f * X + d * ((1.0f - V) + logf(V)))) break;
    u32 nk0, nk1, xk0, xk1, uk0, uk1;
    jx_subkey(K0, K1, 3u, 0u, nk0, nk1);
    jx_subkey(K0, K1, 3u, 1u, xk0, xk1);
    jx_subkey(K0, K1, 3u, 2u, uk0, uk1);
    K0 = nk0; K1 = nk1;
    float x, v;
    u32 c0 = xk0, c1 = xk1;
    do {
      u32 t0, t1, s0, s1;
      jx_subkey(c0, c1, 2u, 0u, t0, t1);
      jx_subkey(c0, c1, 2u, 1u, s0, s1);
      c0 = t0; c1 = t1;
      x = normal_from_bits(jx_bits(s0, s1, 1u, 0u));
      v = 1.0f + x * c;
    } while (v <= 0.0f);
    X = x * x;
    V = (v * v) * v;
    U = u01_from_bits(jx_bits(uk0, uk1, 1u, 0u));
  }
  const float sample = d * V;
  const float boost = boost_mask ? 1.0f : powf(u_boost, 1.0f / alpha_orig);
  return sample * boost;
}

__device__ inline float sigm(float x) { return 1.0f / (1.0f + expf(-x)); }
__device__ inline float softplusf(float x) { return fmaxf(x, 0.0f) + log1pf(expf(-fabsf(x))); }

// cross-lane broadcast on the VALU pipe (not DS): v_readlane -> SGPR (ctx kernel)
__device__ inline float rl_f(float v, int l) {
  return __int_as_float(__builtin_amdgcn_readlane(__float_as_int(v), l));
}

// ---------------- workspace layout (floats) ----------------
enum : size_t {
  OFF_INP  = 0,
  OFF_CT   = OFF_INP + (size_t)NB * TM1 * NIN,
  OFF_TS   = OFF_CT + (size_t)NB * CTX,
  OFF_LTS  = OFF_TS + NB,
  OFF_DF   = OFF_LTS + NB,
  OFF_LOC  = OFF_DF + (size_t)NB * CTX,
  OFF_SC   = OFF_LOC + (size_t)NB * CTX,
  OFF_H0F  = OFF_SC + (size_t)NB * CTX,
  OFF_C0F  = OFF_H0F + (size_t)NB * HID,
  OFF_H1F  = OFF_C0F + (size_t)NB * HID,
  OFF_C1F  = OFF_H1F + (size_t)NB * HID,
  OFF_YH   = OFF_C1F + (size_t)NB * HID,
  OFF_WTX  = OFF_YH + (size_t)RTOT * TM1,     // Wih0^T padded [16][256] (ctx kernel)
  OFF_WT00 = OFF_WTX + 4096,                  // Whh0^T [64][256]
  OFF_WT10 = OFF_WT00 + 16384,                // Wih1^T [64][256]
  OFF_WT11 = OFF_WT10 + 16384,                // Whh1^T [64][256]
  OFF_WH   = OFF_WT11 + 16384,                // fp16 kpair weights, 53248 halves
  OFF_RND  = OFF_WH + 26624,                  // decode randoms [NSTEP][RTOT][4]
  WS_FLOATS = OFF_RND + (size_t)NSTEP * RTOT * 4
};

// fp16 weight blob segment offsets (in halves)
#define WH_X   0
#define WH_00  4096
#define WH_10  20480
#define WH_11  36864
#define WH_TOT 53248

// ---------------- kernel 0a: transpose weights (fp32, ctx kernel) -----------
__global__ void __launch_bounds__(256) wtrans_kernel(
    const float* __restrict__ Wih0, const float* __restrict__ Whh0,
    const float* __restrict__ Wih1, const float* __restrict__ Whh1,
    float* __restrict__ WTx, float* __restrict__ WT00,
    float* __restrict__ WT10, float* __restrict__ WT11)
{
  const int i = blockIdx.x * 256 + threadIdx.x;   // < 53248
  if (i < 4096) {
    const int k = i >> 8, g = i & 255;
    WTx[i] = (k < 15) ? Wih0[g * 15 + k] : 0.0f;
  } else if (i < 4096 + 16384) {
    const int j = i - 4096, k = j >> 8, g = j & 255;
    WT00[j] = Whh0[g * 64 + k];
  } else if (i < 4096 + 32768) {
    const int j = i - 4096 - 16384, k = j >> 8, g = j & 255;
    WT10[j] = Wih1[g * 64 + k];
  } else {
    const int j = i - 4096 - 32768, k = j >> 8, g = j & 255;
    WT11[j] = Whh1[g * 64 + k];
  }
}

// ---------------- kernel 0a2: fp16 kpair-interleaved weights for decode ------
// R2 gate-QUARTER layout: half index j (within segment): kp=j>>9; r=j&511;
// l=r>>3 (lane); g4=(r>>1)&3; ke=r&1;  gate g = 64*g4 + l; k = 2*kp+ke.
// Lane l computes gates {l,64+l,128+l,192+l} = (i,f,g,o) for hid=l directly,
// so the cell nonlinearity needs NO gate transpose (g_s eliminated).
__global__ void __launch_bounds__(256) wh_kernel(
    const float* __restrict__ Wih0, const float* __restrict__ Whh0,
    const float* __restrict__ Wih1, const float* __restrict__ Whh1,
    f16* __restrict__ WH)
{
  const int j = blockIdx.x * 256 + threadIdx.x;   // < 53248
  int q, which;
  if (j < WH_00)      { q = j;         which = 0; }
  else if (j < WH_10) { q = j - WH_00; which = 1; }
  else if (j < WH_11) { q = j - WH_10; which = 2; }
  else                { q = j - WH_11; which = 3; }
  const int kp = q >> 9, r = q & 511;
  const int l = r >> 3, g4 = (r >> 1) & 3, ke = r & 1;
  const int g = 64 * g4 + l, k = kp * 2 + ke;
  float v;
  if (which == 0)      v = (k < 15) ? Wih0[g * 15 + k] : 0.0f;
  else if (which == 1) v = Whh0[g * 64 + k];
  else if (which == 2) v = Wih1[g * 64 + k];
  else                 v = Whh1[g * 64 + k];
  WH[j] = (f16)v;
}

// ---------------- kernel 0b: precompute decode randoms -----------------------
__global__ void __launch_bounds__(256) rnd_dec_kernel(
    float* __restrict__ RND, u32 kl0, u32 kl1)
{
  const int i = blockIdx.x * 256 + threadIdx.x;   // < NSTEP*RTOT = 1203200
  const int s = i / RTOT, rg = i - s * RTOT;
  u32 ks0, ks1, skz0, skz1, skg0, skg1;
  tf2x32(kl0, kl1, 0u, (u32)s, ks0, ks1);
  tf2x32(ks0, ks1, 0u, 0u, skz0, skz1);
  tf2x32(ks0, ks1, 0u, 1u, skg0, skg1);
  const float z = normal_from_bits(jx_bits(skz0, skz1, RTOT, (u32)rg));
  u32 gk0, gk1;
  jx_subkey(skg0, skg1, RTOT, (u32)rg, gk0, gk1);
  u32 K0, K1, S0, S1;
  jx_subkey(gk0, gk1, 2u, 0u, K0, K1);
  jx_subkey(gk0, gk1, 2u, 1u, S0, S1);   // boost key, unused (alpha >= 1)
  u32 nk0, nk1, xk0, xk1, uk0, uk1;
  jx_subkey(K0, K1, 3u, 0u, nk0, nk1);
  jx_subkey(K0, K1, 3u, 1u, xk0, xk1);
  jx_subkey(K0, K1, 3u, 2u, uk0, uk1);
  u32 c0 = xk0, c1 = xk1, t0, t1, s0, s1;
  jx_subkey(c0, c1, 2u, 0u, t0, t1);
  jx_subkey(c0, c1, 2u, 1u, s0, s1);
  const float x1 = normal_from_bits(jx_bits(s0, s1, 1u, 0u));
  c0 = t0; c1 = t1;
  jx_subkey(c0, c1, 2u, 0u, t0, t1);
  jx_subkey(c0, c1, 2u, 1u, s0, s1);
  const float x2 = normal_from_bits(jx_bits(s0, s1, 1u, 0u));
  const float U1 = u01_from_bits(jx_bits(uk0, uk1, 1u, 0u));
  float* R = RND + (size_t)i * 4;
  R[0] = z; R[1] = x1; R[2] = x2; R[3] = U1;
}

// ---------------- kernel 1: tscale + feature build ----------------
__global__ void __launch_bounds__(256) prep_kernel(
    const float* __restrict__ X, const float* __restrict__ emb,
    float* __restrict__ inp, float* __restrict__ ct,
    float* __restrict__ tscale, float* __restrict__ ltscale)
{
  const int b = blockIdx.x, t = threadIdx.x;
  __shared__ float red[256];
  __shared__ float ts_sh;
  const float* Xb = X + (size_t)b * LFULL * NCH;
  float p = fabsf(Xb[(28 + t) * NCH]);
  if (t < 80) p += fabsf(Xb[(28 + 256 + t) * NCH]);
  red[t] = p;
  for (int st = 128; st > 0; st >>= 1) { __syncthreads(); if (t < st) red[t] += red[t + st]; }
  __syncthreads();
  if (t == 0) {
    float ts = red[0] / 336.0f;
    ts = fmaxf(ts, 1e-10f);
    tscale[b] = ts; ltscale[b] = logf(ts); ts_sh = ts;
  }
  __syncthreads();
  const float ts = ts_sh;
  const float lts = logf(ts);
  const float ev = emb[0];
  for (int idx = t; idx < TM1 * NIN; idx += 256) {
    const int tt = idx / NIN, f = idx - tt * NIN;
    float val;
    if (f == 0)       val = (tt < CTX) ? Xb[(28 + tt) * NCH] / ts : 0.0f;
    else if (f <= 10) val = (tt < CTX) ? Xb[(28 + tt - c_LAGS[f - 1]) * NCH] / ts : 0.0f;
    else if (f == 11) val = ev;
    else if (f == 12) val = Xb[(28 + tt) * NCH + 2];
    else if (f == 13) val = lts;
    else              val = Xb[(28 + tt) * NCH + 1];
    inp[(size_t)(b * TM1 + tt) * NIN + f] = val;
    if (f == 0 && tt < CTX) ct[b * CTX + tt] = val;
  }
}

// ---------------- kernel 2: context LSTM (unchanged, exact fp32) -------------
__global__ void __launch_bounds__(256) ctx_lstm_kernel(
    const float* __restrict__ inp,
    const float* __restrict__ WTx, const float* __restrict__ WT00,
    const float* __restrict__ WT10, const float* __restrict__ WT11,
    const float* __restrict__ bih0, const float* __restrict__ bhh0,
    const float* __restrict__ bih1, const float* __restrict__ bhh1,
    const float* __restrict__ wdf, const float* __restrict__ bdfp,
    const float* __restrict__ wloc, const float* __restrict__ blocp,
    const float* __restrict__ wsc, const float* __restrict__ bscp,
    float* __restrict__ dfo, float* __restrict__ loco, float* __restrict__ sco,
    float* __restrict__ h0f, float* __restrict__ c0f,
    float* __restrict__ h1f, float* __restrict__ c1f)
{
  const int b = blockIdx.x, t = threadIdx.x;
  const int lane = t & 63, w = t >> 6;
  const int gbase = lane << 2;
  __shared__ __align__(16) float gA[4][256];
  __shared__ __align__(16) float gB[4][256];

  const float bs0 = bih0[lane]       + bhh0[lane];
  const float bs1 = bih0[64 + lane]  + bhh0[64 + lane];
  const float bs2 = bih0[128 + lane] + bhh0[128 + lane];
  const float bs3 = bih0[192 + lane] + bhh0[192 + lane];
  const float bs4 = bih1[lane]       + bhh1[lane];
  const float bs5 = bih1[64 + lane]  + bhh1[64 + lane];
  const float bs6 = bih1[128 + lane] + bhh1[128 + lane];
  const float bs7 = bih1[192 + lane] + bhh1[192 + lane];
  const float wdfv = wdf[lane], wlocv = wloc[lane], wscv = wsc[lane];
  const float bdf = bdfp[0], bloc = blocp[0], bsc = bscp[0];

  float h0r = 0.f, h1r = 0.f, c0r = 0.f, c1r = 0.f;
  const float* inb = inp + (size_t)b * TM1 * NIN;
  const int kx = w * 4;    // x-part k-quarter
  const int kh = w * 16;   // h-part k-quarter

  for (int tt = 0; tt < CTX; tt++) {
    float xr = 0.f;
    if (lane < 15) xr = inb[tt * NIN + lane];

    v2f aA = bc2(0.0f), aB = bc2(0.0f);
#pragma unroll
    for (int kk = 0; kk < 4; kk++) {
      const int k = kx + kk;
      const float4 wv = *(const float4*)&WTx[(k << 8) + gbase];
      v2f wlo, whi; wlo[0] = wv.x; wlo[1] = wv.y; whi[0] = wv.z; whi[1] = wv.w;
      const v2f hk = bc2(rl_f(xr, k));
      aA += wlo * hk; aB += whi * hk;
    }
#pragma unroll
    for (int kk = 0; kk < 16; kk++) {
      const int k = kh + kk;
      const float4 wv = *(const float4*)&WT00[(k << 8) + gbase];
      v2f wlo, whi; wlo[0] = wv.x; wlo[1] = wv.y; whi[0] = wv.z; whi[1] = wv.w;
      const v2f hk = bc2(rl_f(h0r, k));
      aA += wlo * hk; aB += whi * hk;
    }
    {
      float4 gv; gv.x = aA[0]; gv.y = aA[1]; gv.z = aB[0]; gv.w = aB[1];
      *(float4*)&gA[w][gbase] = gv;
    }
    __syncthreads();

    {
      float gi = ((gA[0][lane]       + gA[1][lane])       + gA[2][lane])       + gA[3][lane];
      float gf = ((gA[0][64 + lane]  + gA[1][64 + lane])  + gA[2][64 + lane])  + gA[3][64 + lane];
      float gg = ((gA[0][128 + lane] + gA[1][128 + lane]) + gA[2][128 + lane]) + gA[3][128 + lane];
      float go = ((gA[0][192 + lane] + gA[1][192 + lane]) + gA[2][192 + lane]) + gA[3][192 + lane];
      gi += bs0; gf += bs1; gg += bs2; go += bs3;
      c0r = sigm(gf) * c0r + sigm(gi) * tanhf(gg);
      h0r = sigm(go) * tanhf(c0r);
    }

    aA = bc2(0.0f); aB = bc2(0.0f);
#pragma unroll
    for (int kk = 0; kk < 16; kk++) {
      const int k = kh + kk;
      const float4 wv = *(const float4*)&WT10[(k << 8) + gbase];
      v2f wlo, whi; wlo[0] = wv.x; wlo[1] = wv.y; whi[0] = wv.z; whi[1] = wv.w;
      const v2f hk = bc2(rl_f(h0r, k));
      aA += wlo * hk; aB += whi * hk;
    }
#pragma unroll
    for (int kk = 0; kk < 16; kk++) {
      const int k = kh + kk;
      const float4 wv = *(const float4*)&WT11[(k << 8) + gbase];
      v2f wlo, whi; wlo[0] = wv.x; wlo[1] = wv.y; whi[0] = wv.z; whi[1] = wv.w;
      const v2f hk = bc2(rl_f(h1r, k));
      aA += wlo * hk; aB += whi * hk;
    }
    {
      float4 gv; gv.x = aA[0]; gv.y = aA[1]; gv.z = aB[0]; gv.w = aB[1];
      *(float4*)&gB[w][gbase] = gv;
    }
    __syncthreads();

    {
      float gi = ((gB[0][lane]       + gB[1][lane])       + gB[2][lane])       + gB[3][lane];
      float gf = ((gB[0][64 + lane]  + gB[1][64 + lane])  + gB[2][64 + lane])  + gB[3][64 + lane];
      float gg = ((gB[0][128 + lane] + gB[1][128 + lane]) + gB[2][128 + lane]) + gB[3][128 + lane];
      float go = ((gB[0][192 + lane] + gB[1][192 + lane]) + gB[2][192 + lane]) + gB[3][192 + lane];
      gi += bs4; gf += bs5; gg += bs6; go += bs7;
      c1r = sigm(gf) * c1r + sigm(gi) * tanhf(gg);
      h1r = sigm(go) * tanhf(c1r);
      if (w == 0) {
        float pd = h1r * wdfv, pl = h1r * wlocv, ps = h1r * wscv;
#pragma unroll
        for (int off = 32; off > 0; off >>= 1) {
          pd += __shfl_down(pd, off, 64);
          pl += __shfl_down(pl, off, 64);
          ps += __shfl_down(ps, off, 64);
        }
        if (lane == 0) {
          dfo[b * CTX + tt]  = 2.0f + softplusf(pd + bdf);
          loco[b * CTX + tt] = pl + bloc;
          sco[b * CTX + tt]  = softplusf(ps + bsc);
        }
      }
    }
  }
  if (w == 0) {
    h0f[b * 64 + lane] = h0r; c0f[b * 64 + lane] = c0r;
    h1f[b * 64 + lane] = h1r; c1f[b * 64 + lane] = c1r;
  }
}

// ---------------- kernel 3: context sampling (y_ctx) ----------------
__global__ void __launch_bounds__(256) ctx_sample_kernel(
    const float* __restrict__ df, const float* __restrict__ loc, const float* __restrict__ sc,
    const float* __restrict__ tscale, float* __restrict__ yhat,
    u32 kz0, u32 kz1, u32 kg0, u32 kg1)
{
  const int i = blockIdx.x * 256 + threadIdx.x;
  const int r = i / CTX, t = i - r * CTX;
  const int b = r / NSAMP;
  const float dfv = df[b * CTX + t], lv = loc[b * CTX + t], sv = sc[b * CTX + t];
  const float z = normal_from_bits(jx_bits(kz0, kz1, NCTXS, (u32)i));
  u32 gk0, gk1;
  jx_subkey(kg0, kg1, NCTXS, (u32)i, gk0, gk1);
  const float g = jax_gamma_one(gk0, gk1, dfv * 0.5f);
  const float y = (lv + sv * (z * sqrtf(dfv / (2.0f * g)))) * tscale[b];
  yhat[(size_t)r * TM1 + t] = y;
}

// ---------------- decode MAC helper ------------------------------------------
// NKO k-octets (8 halves of input each = 4 kpairs).  Per octet: 4 weight
// ds_read_b128 (16B lane stride, conflict-free) + per row 1 uniform-address
// ds_read_b128 h-broadcast + 16 v_dot2_f32_f16.  acc[row][g4] where
// g4 = gate-quarter (gate = 64*g4 + lane).
template <int NKO>
__device__ __forceinline__ void mac_seg(const f16* __restrict__ wseg,
                                        const f16* __restrict__ hbase,
                                        const int hstride, float (&acc)[RPW][4],
                                        const int lane)
{
#pragma unroll 2
  for (int ko = 0; ko < NKO; ko++) {
    const h8 wv0 = *(const h8*)&wseg[((4 * ko + 0) << 9) | (lane << 3)];
    const h8 wv1 = *(const h8*)&wseg[((4 * ko + 1) << 9) | (lane << 3)];
    const h8 wv2 = *(const h8*)&wseg[((4 * ko + 2) << 9) | (lane << 3)];
    const h8 wv3 = *(const h8*)&wseg[((4 * ko + 3) << 9) | (lane << 3)];
#pragma unroll
    for (int rr = 0; rr < RPW; rr++) {
      const h8 hv = *(const h8*)&hbase[rr * hstride + (ko << 3)];
      h2 ha, hb, hc, hd;
      ha[0] = hv[0]; ha[1] = hv[1];
      hb[0] = hv[2]; hb[1] = hv[3];
      hc[0] = hv[4]; hc[1] = hv[5];
      hd[0] = hv[6]; hd[1] = hv[7];
#pragma unroll
      for (int g = 0; g < 4; g++) {
        h2 w0, w1, w2, w3;
        w0[0] = wv0[2 * g]; w0[1] = wv0[2 * g + 1];
        w1[0] = wv1[2 * g]; w1[1] = wv1[2 * g + 1];
        w2[0] = wv2[2 * g]; w2[1] = wv2[2 * g + 1];
        w3[0] = wv3[2 * g]; w3[1] = wv3[2 * g + 1];
        float a = acc[rr][g];
        a = dot2(w0, ha, a);
        a = dot2(w1, hb, a);
        a = dot2(w2, hc, a);
        a = dot2(w3, hd, a);
        acc[rr][g] = a;
      }
    }
  }
}

// ---------------- kernel 5: persistent decode ---------------------------------
// R2: gate-quarter layout (no gate transpose, g_s deleted), DROWS=128
// (16 rows/wave, 200 blocks = exactly 1 dispatch round), h-broadcasts as
// uniform ds_read_b128 octets, parallel x-build, RND prefetched at step top.
// Weights LDS-resident fp16 (104 KB), one barrier total, zero in-loop barriers.
__global__ void __launch_bounds__(512) dec_persist_kernel(
    const float* __restrict__ inp, const float* __restrict__ tscale,
    const f16* __restrict__ WH,
    const float* __restrict__ bih0, const float* __restrict__ bhh0,
    const float* __restrict__ bih1, const float* __restrict__ bhh1,
    const float* __restrict__ wdf, const float* __restrict__ bdfp,
    const float* __restrict__ wloc, const float* __restrict__ blocp,
    const float* __restrict__ wsc, const float* __restrict__ bscp,
    const float* __restrict__ h0f, const float* __restrict__ c0f,
    const float* __restrict__ h1f, const float* __restrict__ c1f,
    const float* __restrict__ ct, const float* __restrict__ RND,
    float* __restrict__ yhat, u32 kl0, u32 kl1)
{
  const int t    = threadIdx.x;
  const int lane = t & 63;
  const int w    = t >> 6;        // wave 0..7
  const int r0   = w * RPW;       // wave's first local row

  __shared__ __align__(16) f16   wgt[WH_TOT];       // 104 KB fp16 weights
  __shared__ __align__(16) f16   h0h[DROWS][64];    // 16 KB
  __shared__ __align__(16) f16   h1h[DROWS][64];    // 16 KB
  __shared__ __align__(16) f16   hist[DROWS][32];   // 8 KB lag ring
  __shared__ __align__(16) f16   xh[DROWS][16];     // 4 KB
  __shared__ __align__(16) f16   fst[3][NSTEP][4];  // 1.1 KB feature stash
  __shared__ float prevs[DROWS], tsr[DROWS];
  __shared__ float dfL[DROWS], locL[DROWS], scL[DROWS];
  __shared__ unsigned char rsel[DROWS];

  const int base = blockIdx.x * DROWS;
  const int bblo = base / NSAMP;

  // ---- stage all weights once: 104 x (64 lanes x 16B), 13 per wave ----
#pragma unroll
  for (int i = 0; i < 13; i++) {
    const int off = (i * 8 + w) * 512;   // halves
    __builtin_amdgcn_global_load_lds(
        (const __attribute__((address_space(1))) void*)(WH + off + lane * 8),
        (__attribute__((address_space(3))) void*)(wgt + off), 16, 0, 0);
  }

  float c0reg[RPW], c1reg[RPW];
#pragma unroll
  for (int rr = 0; rr < RPW; rr++) {
    const int bb = (base + r0 + rr) / NSAMP;
    h0h[r0 + rr][lane] = (f16)h0f[bb * 64 + lane];
    h1h[r0 + rr][lane] = (f16)h1f[bb * 64 + lane];
    c0reg[rr] = c0f[bb * 64 + lane];
    c1reg[rr] = c1f[bb * 64 + lane];
  }
  const float bs0 = bih0[lane]       + bhh0[lane];
  const float bs1 = bih0[64 + lane]  + bhh0[64 + lane];
  const float bs2 = bih0[128 + lane] + bhh0[128 + lane];
  const float bs3 = bih0[192 + lane] + bhh0[192 + lane];
  const float bs4 = bih1[lane]       + bhh1[lane];
  const float bs5 = bih1[64 + lane]  + bhh1[64 + lane];
  const float bs6 = bih1[128 + lane] + bhh1[128 + lane];
  const float bs7 = bih1[192 + lane] + bhh1[192 + lane];
  const float wdfv = wdf[lane], wlocv = wloc[lane], wscv = wsc[lane];
  const float bdf = bdfp[0], bloc = blocp[0], bsc = bscp[0];

  for (int idx = t; idx < DROWS * 28; idx += 512) {
    const int i = idx / 28, k = idx - i * 28;
    const int bb = (base + i) / NSAMP;
    hist[i][31 - k] = (f16)ct[bb * CTX + 335 - k];
  }
  // feature stash: rows of a 128-row block span at most 3 batch indices
  for (int idx = t; idx < 3 * NSTEP * 4; idx += 512) {
    const int sel = idx / (NSTEP * 4), rem = idx - sel * (NSTEP * 4);
    const int s = rem >> 2, f = rem & 3;
    const int bb = min(bblo + sel, NB - 1);
    fst[sel][s][f] = (f16)inp[((size_t)bb * TM1 + CTX + s) * NIN + 11 + f];
  }
  if (t < DROWS) {
    const int rg = base + t;
    prevs[t] = yhat[(size_t)rg * TM1 + 335];
    tsr[t] = tscale[rg / NSAMP];
    xh[t][15] = (f16)0.0f;            // pad slot (weights there are 0 too)
    rsel[t] = (unsigned char)((rg / NSAMP) - bblo);
  }
  __syncthreads();   // covers weight staging (vmcnt drain) + all init writes

  for (int s = 0; s < NSTEP; s++) {
    // ---- prefetch this step's randoms (hides HBM/L2 latency under MAC) ----
    float rz = 0.f, rx1 = 0.f, rx2 = 0.f, rU = 0.f;
    if (lane < RPW) {
      const float4 R = *(const float4*)(RND + ((size_t)s * RTOT + base + r0 + lane) * 4);
      rz = R.x; rx1 = R.y; rx2 = R.z; rU = R.w;
    }

    // ---- parallel x-build ----
    if (lane < RPW) {
      const int row = r0 + lane;
      const float nv = prevs[row] / tsr[row];
      const f16 nh = (f16)nv;
      xh[row][0] = nh;
      hist[row][s & 31] = nh;
    }
    {
      const int rq = lane >> 2, q = lane & 3;
      const int row = r0 + rq;
#pragma unroll
      for (int p = 0; p < 4; p++) {
        const int sl = 1 + q + p * 4;          // 1..16
        if (sl <= 10) {
          xh[row][sl] = hist[row][(s - c_LAGS[sl - 1]) & 31];
        } else if (sl <= 14) {
          xh[row][sl] = fst[rsel[row]][s][sl - 11];
        }
      }
    }

    float acc[RPW][4];
#pragma unroll
    for (int rr = 0; rr < RPW; rr++) {
      acc[rr][0] = 0.f; acc[rr][1] = 0.f; acc[rr][2] = 0.f; acc[rr][3] = 0.f;
    }

    // ---- layer 0 gates: x part + h0_prev part ----
    mac_seg<2>(wgt + WH_X, &xh[r0][0], 16, acc, lane);
    mac_seg<8>(wgt + WH_00, &h0h[r0][0], 64, acc, lane);

    // ---- cell 0 (lane = hid, no transpose) ----
#pragma unroll
    for (int rr = 0; rr < RPW; rr++) {
      const float gi = acc[rr][0] + bs0;
      const float gf = acc[rr][1] + bs1;
      const float gg = acc[rr][2] + bs2;
      const float go = acc[rr][3] + bs3;
      float c0 = c0reg[rr];
      c0 = sigm(gf) * c0 + sigm(gi) * tanhf(gg);
      c0reg[rr] = c0;
      h0h[r0 + rr][lane] = (f16)(sigm(go) * tanhf(c0));
    }

#pragma unroll
    for (int rr = 0; rr < RPW; rr++) {
      acc[rr][0] = 0.f; acc[rr][1] = 0.f; acc[rr][2] = 0.f; acc[rr][3] = 0.f;
    }

    // ---- layer 1 gates: h0_new part + h1_prev part ----
    mac_seg<8>(wgt + WH_10, &h0h[r0][0], 64, acc, lane);
    mac_seg<8>(wgt + WH_11, &h1h[r0][0], 64, acc, lane);

    // ---- cell 1 + head ----
#pragma unroll
    for (int rr = 0; rr < RPW; rr++) {
      const int row = r0 + rr;
      const float gi = acc[rr][0] + bs4;
      const float gf = acc[rr][1] + bs5;
      const float gg = acc[rr][2] + bs6;
      const float go = acc[rr][3] + bs7;
      float c1 = c1reg[rr];
      c1 = sigm(gf) * c1 + sigm(gi) * tanhf(gg);
      c1reg[rr] = c1;
      const float h1v = sigm(go) * tanhf(c1);
      h1h[row][lane] = (f16)h1v;
      float pd = h1v * wdfv, pl = h1v * wlocv, ps = h1v * wscv;
#pragma unroll
      for (int off = 32; off > 0; off >>= 1) {
        pd += __shfl_down(pd, off, 64);
        pl += __shfl_down(pl, off, 64);
        ps += __shfl_down(ps, off, 64);
      }
      if (lane == 0) {
        dfL[row]  = 2.0f + softplusf(pd + bdf);
        locL[row] = pl + bloc;
        scL[row]  = softplusf(ps + bsc);
      }
    }

    // ---- sample (one lane per row, 16 rows in parallel) ----
    if (lane < RPW) {
      const int row = r0 + lane, rg = base + row;
      const float dfv = dfL[row], lv = locL[row], scv = scL[row];
      const float z = rz;
      const float alpha = dfv * 0.5f;
      float gam;
      {
#pragma clang fp contract(off)
        const float d = alpha - 0.33333334f;
        const float c = 0.33333334f / sqrtf(d);
        float x = rx1;
        float v = 1.0f + x * c;
        bool ok = true;
        if (v <= 0.0f) { x = rx2; v = 1.0f + x * c; ok = (v > 0.0f); }
        const float X = x * x;
        const float V = (v * v) * v;
        const float U = rU;
        bool accept = false;
        if (ok) {
          if (!(U >= 1.0f - 0.0331f * (X * X))) accept = true;
          else if (!(logf(U) >= 0.5f * X + d * ((1.0f - V) + logf(V)))) accept = true;
        }
        if (accept) {
          gam = d * V;
        } else {
          u32 ks0, ks1, skg0, skg1, gk0, gk1;
          tf2x32(kl0, kl1, 0u, (u32)s, ks0, ks1);
          tf2x32(ks0, ks1, 0u, 1u, skg0, skg1);
          jx_subkey(skg0, skg1, RTOT, (u32)rg, gk0, gk1);
          gam = jax_gamma_one(gk0, gk1, alpha);
        }
      }
      const float y = (lv + scv * (z * sqrtf(dfv / (2.0f * gam)))) * tsr[row];
      yhat[(size_t)rg * TM1 + CTX + s] = y;
      prevs[row] = y;
    }
  }
}

// ---------------- kernel 6: median over 100 samples per (b,t) ----------------
__global__ void __launch_bounds__(256) median_kernel(
    const float* __restrict__ yhat, float* __restrict__ out)
{
  __shared__ float vals[4][100];
  const int wave = threadIdx.x >> 6, lane = threadIdx.x & 63;
  const int cell = blockIdx.x * 4 + wave;
  const int b = cell / TM1, t = cell - b * TM1;
  const float* basep = yhat + (size_t)b * NSAMP * TM1 + t;
  const float v1 = basep[(size_t)lane * TM1];
  vals[wave][lane] = v1;
  float v2 = 0.f;
  if (lane < 36) { v2 = basep[(size_t)(64 + lane) * TM1]; vals[wave][64 + lane] = v2; }
  __syncthreads();
  int cl1 = 0, ce1 = 0, cl2 = 0, ce2 = 0;
  for (int jj = 0; jj < 100; jj++) {
    const float w = vals[wave][jj];
    cl1 += (w < v1); ce1 += (w == v1);
    cl2 += (w < v2); ce2 += (w == v2);
  }
  if (cl1 <= 49 && 49 < cl1 + ce1) out[cell] = v1;
  if (lane < 36 && cl2 <= 49 && 49 < cl2 + ce2) out[cell] = v2;
}

// ---------------- launch ----------------
extern "C" void kernel_launch(void* const* d_in, const int* in_sizes, int n_in,
                              void* d_out, int out_size, void* d_ws, size_t ws_size,
                              hipStream_t stream) {
  (void)in_sizes; (void)n_in; (void)out_size; (void)ws_size;
  const float* X     = (const float*)d_in[0];
  const float* Wih0  = (const float*)d_in[2];
  const float* Whh0  = (const float*)d_in[3];
  const float* bih0  = (const float*)d_in[4];
  const float* bhh0  = (const float*)d_in[5];
  const float* Wih1  = (const float*)d_in[6];
  const float* Whh1  = (const float*)d_in[7];
  const float* bih1  = (const float*)d_in[8];
  const float* bhh1  = (const float*)d_in[9];
  const float* wdf   = (const float*)d_in[10];
  const float* bdf   = (const float*)d_in[11];
  const float* wloc  = (const float*)d_in[12];
  const float* bloc  = (const float*)d_in[13];
  const float* wsc   = (const float*)d_in[14];
  const float* bsc   = (const float*)d_in[15];
  const float* emb   = (const float*)d_in[16];

  float* wsf = (float*)d_ws;
  float* inp  = wsf + OFF_INP;
  float* ct   = wsf + OFF_CT;
  float* ts   = wsf + OFF_TS;
  float* lts  = wsf + OFF_LTS;
  float* dfp  = wsf + OFF_DF;
  float* locp = wsf + OFF_LOC;
  float* scp  = wsf + OFF_SC;
  float* h0f  = wsf + OFF_H0F;
  float* c0f  = wsf + OFF_C0F;
  float* h1f  = wsf + OFF_H1F;
  float* c1f  = wsf + OFF_C1F;
  float* yhat = wsf + OFF_YH;
  float* wtx  = wsf + OFF_WTX;
  float* wt00 = wsf + OFF_WT00;
  float* wt10 = wsf + OFF_WT10;
  float* wt11 = wsf + OFF_WT11;
  f16*   wh   = (f16*)(wsf + OFF_WH);
  float* rnd  = wsf + OFF_RND;

  const u32 key0 = 0u, key1 = 42u;
  u32 kc0, kc1, kl0, kl1;
  jx_subkey(key0, key1, 2u, 0u, kc0, kc1);
  jx_subkey(key0, key1, 2u, 1u, kl0, kl1);
  u32 kz0, kz1, kg0, kg1;
  jx_subkey(kc0, kc1, 2u, 0u, kz0, kz1);
  jx_subkey(kc0, kc1, 2u, 1u, kg0, kg1);

  wtrans_kernel<<<208, 256, 0, stream>>>(Wih0, Whh0, Wih1, Whh1, wtx, wt00, wt10, wt11);
  wh_kernel<<<208, 256, 0, stream>>>(Wih0, Whh0, Wih1, Whh1, wh);
  rnd_dec_kernel<<<(NSTEP * RTOT) / 256, 256, 0, stream>>>(rnd, kl0, kl1);
  prep_kernel<<<NB, 256, 0, stream>>>(X, emb, inp, ct, ts, lts);
  ctx_lstm_kernel<<<NB, 256, 0, stream>>>(inp, wtx, wt00, wt10, wt11,
                                          bih0, bhh0, bih1, bhh1,
                                          wdf, bdf, wloc, bloc, wsc, bsc,
                                          dfp, locp, scp, h0f, c0f, h1f, c1f);
  ctx_sample_kernel<<<NCTXS / 256, 256, 0, stream>>>(dfp, locp, scp, ts, yhat, kz0, kz1, kg0, kg1);
  dec_persist_kernel<<<DBLOCKS, 512, 0, stream>>>(inp, ts, wh,
                                                  bih0, bhh0, bih1, bhh1,
                                                  wdf, bdf, wloc, bloc, wsc, bsc,
                                                  h0f, c0f, h1f, c1f, ct, rnd, yhat, kl0, kl1);
  median_kernel<<<(NB * TM1) / 4, 256, 0, stream>>>(yhat, (float*)d_out);
}

// Round 5
// 3417.998 us; speedup vs baseline: 1.5528x; 1.3715x over previous
//
#include <hip/hip_runtime.h>
#include <stdint.h>
#include <stddef.h>

typedef uint32_t u32;
typedef float v2f __attribute__((ext_vector_type(2)));
typedef _Float16 f16;
typedef f16 half4 __attribute__((ext_vector_type(4)));
typedef f16 half8 __attribute__((ext_vector_type(8)));
typedef float floatx4 __attribute__((ext_vector_type(4)));

// ---------------- problem constants (fixed by reference file) ----------------
#define NB    256      // batch B
#define LFULL 412      // L
#define NCH   3        // C
#define CTX   336      // context_length
#define NSAMP 100      // n_samples
#define TM1   383      // T-1 (T = L - MAX_LAG = 384)
#define HID   64
#define NIN   15
#define RTOT  25600    // NB*NSAMP
#define NCTXS 8601600u // RTOT*CTX
#define NSTEP 47       // H-1

#define DROWS   128    // rows per persistent decode block (16 per wave, 8 waves)
#define RPW     16     // rows per wave
#define DBLOCKS (RTOT / DROWS)  // 200 -> 1 dispatch round on 256 CUs

#define HSTR    72     // h-array LDS stride in halves (144 B, 16B-aligned, bank-spread)

#define JAX_PARTITIONABLE 1

__device__ const int c_LAGS[10] = {1,2,3,4,5,6,7,14,21,28};

__device__ inline v2f bc2(float x) { v2f r; r[0] = x; r[1] = x; return r; }

// ---------------- threefry2x32 (matches jax._src.prng) ----------------
__host__ __device__ inline void tf2x32(u32 k0, u32 k1, u32 x0, u32 x1, u32& o0, u32& o1) {
  const u32 ks2 = k0 ^ k1 ^ 0x1BD11BDAu;
#define TFR(r) { x0 += x1; x1 = (x1 << (r)) | (x1 >> (32 - (r))); x1 ^= x0; }
  x0 += k0; x1 += k1;
  TFR(13) TFR(15) TFR(26) TFR(6)
  x0 += k1; x1 += ks2 + 1u;
  TFR(17) TFR(29) TFR(16) TFR(24)
  x0 += ks2; x1 += k0 + 2u;
  TFR(13) TFR(15) TFR(26) TFR(6)
  x0 += k0; x1 += k1 + 3u;
  TFR(17) TFR(29) TFR(16) TFR(24)
  x0 += k1; x1 += ks2 + 4u;
  TFR(13) TFR(15) TFR(26) TFR(6)
  x0 += ks2; x1 += k0 + 5u;
#undef TFR
  o0 = x0; o1 = x1;
}

__host__ __device__ inline u32 split_word_legacy(u32 k0, u32 k1, u32 n, u32 j) {
  u32 o0, o1;
  if (j < n) { tf2x32(k0, k1, j, n + j, o0, o1); return o0; }
  tf2x32(k0, k1, j - n, j, o0, o1); return o1;
}

__host__ __device__ inline void jx_subkey(u32 k0, u32 k1, u32 n, u32 i, u32& s0, u32& s1) {
#if JAX_PARTITIONABLE
  (void)n; tf2x32(k0, k1, 0u, i, s0, s1);
#else
  s0 = split_word_legacy(k0, k1, n, 2u * i);
  s1 = split_word_legacy(k0, k1, n, 2u * i + 1u);
#endif
}

__device__ inline u32 jx_bits(u32 k0, u32 k1, u32 n, u32 i) {
#if JAX_PARTITIONABLE
  (void)n; u32 o0, o1; tf2x32(k0, k1, 0u, i, o0, o1); return o0 ^ o1;
#else
  u32 o0, o1;
  if (n == 1u) { tf2x32(k0, k1, 0u, 0u, o0, o1); return o0; }
  const u32 h = n >> 1;
  if (i < h) { tf2x32(k0, k1, i, h + i, o0, o1); return o0; }
  tf2x32(k0, k1, i - h, i, o0, o1); return o1;
#endif
}

// ---------------- JAX-exact float transforms ----------------
__device__ inline float jax_erfinv(float x) {
#pragma clang fp contract(off)
  float w = -log1pf(-x * x);
  float p;
  if (w < 5.0f) {
    w = w - 2.5f;
    p = 2.81022636e-08f;
    p = 3.43273939e-07f + p * w;
    p = -3.5233877e-06f + p * w;
    p = -4.39150654e-06f + p * w;
    p = 0.00021858087f + p * w;
    p = -0.00125372503f + p * w;
    p = -0.00417768164f + p * w;
    p = 0.246640727f + p * w;
    p = 1.50140941f + p * w;
  } else {
    w = sqrtf(w) - 3.0f;
    p = -0.000200214257f;
    p = 0.000100950558f + p * w;
    p = 0.00134934322f + p * w;
    p = -0.00367342844f + p * w;
    p = 0.00573950773f + p * w;
    p = -0.0076224613f + p * w;
    p = 0.00943887047f + p * w;
    p = 1.00167406f + p * w;
    p = 2.83297682f + p * w;
  }
  return p * x;
}

__device__ inline float u01_from_bits(u32 bits) {
  return __uint_as_float((bits >> 9) | 0x3f800000u) - 1.0f;
}

__device__ inline float normal_from_bits(u32 bits) {
#pragma clang fp contract(off)
  const float lo = -0.99999994f;
  const float u = u01_from_bits(bits);
  float r = u * 2.0f + lo;
  r = fmaxf(lo, r);
  return 1.41421356f * jax_erfinv(r);
}

__device__ float jax_gamma_one(u32 k0, u32 k1, float alpha) {
#pragma clang fp contract(off)
  const bool boost_mask = (alpha >= 1.0f);
  const float alpha_orig = alpha;
  const float a = boost_mask ? alpha : (alpha + 1.0f);
  const float d = a - 0.33333334f;
  const float c = 0.33333334f / sqrtf(d);
  u32 K0, K1, S0, S1;
  jx_subkey(k0, k1, 2u, 0u, K0, K1);
  jx_subkey(k0, k1, 2u, 1u, S0, S1);
  float u_boost = 1.0f;
  if (!boost_mask) u_boost = u01_from_bits(jx_bits(S0, S1, 1u, 0u));
  float X = 0.0f, V = 1.0f, U = 2.0f;
  while (true) {
    if (!(U >= 1.0f - 0.0331f * (X * X))) break;
    if (!(logf(U) >= 0.5f * X + d * ((1.0f - V) + logf(V)))) break;
    u32 nk0, nk1, xk0, xk1, uk0, uk1;
    jx_subkey(K0, K1, 3u, 0u, nk0, nk1);
    jx_subkey(K0, K1, 3u, 1u, xk0, xk1);
    jx_subkey(K0, K1, 3u, 2u, uk0, uk1);
    K0 = nk0; K1 = nk1;
    float x, v;
    u32 c0 = xk0, c1 = xk1;
    do {
      u32 t0, t1, s0, s1;
      jx_subkey(c0, c1, 2u, 0u, t0, t1);
      jx_subkey(c0, c1, 2u, 1u, s0, s1);
      c0 = t0; c1 = t1;
      x = normal_from_bits(jx_bits(s0, s1, 1u, 0u));
      v = 1.0f + x * c;
    } while (v <= 0.0f);
    X = x * x;
    V = (v * v) * v;
    U = u01_from_bits(jx_bits(uk0, uk1, 1u, 0u));
  }
  const float sample = d * V;
  const float boost = boost_mask ? 1.0f : powf(u_boost, 1.0f / alpha_orig);
  return sample * boost;
}

__device__ inline float sigm(float x) { return 1.0f / (1.0f + expf(-x)); }
__device__ inline float softplusf(float x) { return fmaxf(x, 0.0f) + log1pf(expf(-fabsf(x))); }

// cross-lane broadcast on the VALU pipe (not DS): v_readlane -> SGPR (ctx kernel)
__device__ inline float rl_f(float v, int l) {
  return __int_as_float(__builtin_amdgcn_readlane(__float_as_int(v), l));
}

// ---------------- workspace layout (floats) ----------------
enum : size_t {
  OFF_INP  = 0,
  OFF_CT   = OFF_INP + (size_t)NB * TM1 * NIN,
  OFF_TS   = OFF_CT + (size_t)NB * CTX,
  OFF_LTS  = OFF_TS + NB,
  OFF_DF   = OFF_LTS + NB,
  OFF_LOC  = OFF_DF + (size_t)NB * CTX,
  OFF_SC   = OFF_LOC + (size_t)NB * CTX,
  OFF_H0F  = OFF_SC + (size_t)NB * CTX,
  OFF_C0F  = OFF_H0F + (size_t)NB * HID,
  OFF_H1F  = OFF_C0F + (size_t)NB * HID,
  OFF_C1F  = OFF_H1F + (size_t)NB * HID,
  OFF_YH   = OFF_C1F + (size_t)NB * HID,
  OFF_WTX  = OFF_YH + (size_t)RTOT * TM1,     // Wih0^T padded [16][256] (ctx kernel)
  OFF_WT00 = OFF_WTX + 4096,                  // Whh0^T [64][256]
  OFF_WT10 = OFF_WT00 + 16384,                // Wih1^T [64][256]
  OFF_WT11 = OFF_WT10 + 16384,                // Whh1^T [64][256]
  OFF_WH   = OFF_WT11 + 16384,                // fp16 MFMA-fragment weights, 53248 halves
  OFF_RND  = OFF_WH + 26624,                  // decode randoms [NSTEP][RTOT][4]
  WS_FLOATS = OFF_RND + (size_t)NSTEP * RTOT * 4
};

// fp16 weight blob segment offsets (in halves)
#define WH_X   0        // layer0 x-part: 16 nt x (32 lanes x 8 halves) 16x16x32 B-frags, k<16 only
#define WH_00  4096     // layer0 h-part: 16 nt x 2 kchunk x (64 x 8)   16x16x32 B-frags
#define WH_10  20480    // layer1 h0-part
#define WH_11  36864    // layer1 h1-part
#define WH_TOT 53248

// ---------------- kernel 0a: transpose weights (fp32, ctx kernel) -----------
__global__ void __launch_bounds__(256) wtrans_kernel(
    const float* __restrict__ Wih0, const float* __restrict__ Whh0,
    const float* __restrict__ Wih1, const float* __restrict__ Whh1,
    float* __restrict__ WTx, float* __restrict__ WT00,
    float* __restrict__ WT10, float* __restrict__ WT11)
{
  const int i = blockIdx.x * 256 + threadIdx.x;   // < 53248
  if (i < 4096) {
    const int k = i >> 8, g = i & 255;
    WTx[i] = (k < 15) ? Wih0[g * 15 + k] : 0.0f;
  } else if (i < 4096 + 16384) {
    const int j = i - 4096, k = j >> 8, g = j & 255;
    WT00[j] = Whh0[g * 64 + k];
  } else if (i < 4096 + 32768) {
    const int j = i - 4096 - 16384, k = j >> 8, g = j & 255;
    WT10[j] = Wih1[g * 64 + k];
  } else {
    const int j = i - 4096 - 32768, k = j >> 8, g = j & 255;
    WT11[j] = Whh1[g * 64 + k];
  }
}

// ---------------- kernel 0a2: fp16 MFMA B-fragment weights for decode --------
// All fragments now use the SINGLE verified shape 16x16x32 (m89/m97 family):
//  h-part:  lane l holds B[k=kc*32+(l>>4)*8+e][n=nt*16+(l&15)], e=0..7 (16B/lane)
//  x-part:  K=32 zero-padded; only lanes 0..31 (k<16) carry real weights, so
//           each nt block is 256 halves. Lanes 32..63 read overflow garbage
//           from the next block at runtime — killed by zero A elements
//           (xh slots 15..31 are hard zeros; products pair A[k] with B[k]).
__global__ void __launch_bounds__(256) wh_kernel(
    const float* __restrict__ Wih0, const float* __restrict__ Whh0,
    const float* __restrict__ Wih1, const float* __restrict__ Whh1,
    f16* __restrict__ WH)
{
  const int j = blockIdx.x * 256 + threadIdx.x;   // < 53248
  if (j < WH_00) {
    const int nt = j >> 8, rem = j & 255;
    const int l = rem >> 3, e = rem & 7;          // l = 0..31
    const int g = nt * 16 + (l & 15);
    const int k = (l >> 4) * 8 + e;               // k = 0..15
    WH[j] = (f16)((k < 15) ? Wih0[g * 15 + k] : 0.0f);
  } else {
    const float* W; int q;
    if (j < WH_10)      { W = Whh0; q = j - WH_00; }
    else if (j < WH_11) { W = Wih1; q = j - WH_10; }
    else                { W = Whh1; q = j - WH_11; }
    const int blk = q >> 9, rem = q & 511;   // blk = nt*2 + kc
    const int l = rem >> 3, e = rem & 7;
    const int nt = blk >> 1, kc = blk & 1;
    const int g = nt * 16 + (l & 15);
    const int k = kc * 32 + (l >> 4) * 8 + e;
    WH[j] = (f16)W[g * 64 + k];
  }
}

// ---------------- kernel 0b: precompute decode randoms -----------------------
__global__ void __launch_bounds__(256) rnd_dec_kernel(
    float* __restrict__ RND, u32 kl0, u32 kl1)
{
  const int i = blockIdx.x * 256 + threadIdx.x;   // < NSTEP*RTOT = 1203200
  const int s = i / RTOT, rg = i - s * RTOT;
  u32 ks0, ks1, skz0, skz1, skg0, skg1;
  tf2x32(kl0, kl1, 0u, (u32)s, ks0, ks1);
  tf2x32(ks0, ks1, 0u, 0u, skz0, skz1);
  tf2x32(ks0, ks1, 0u, 1u, skg0, skg1);
  const float z = normal_from_bits(jx_bits(skz0, skz1, RTOT, (u32)rg));
  u32 gk0, gk1;
  jx_subkey(skg0, skg1, RTOT, (u32)rg, gk0, gk1);
  u32 K0, K1, S0, S1;
  jx_subkey(gk0, gk1, 2u, 0u, K0, K1);
  jx_subkey(gk0, gk1, 2u, 1u, S0, S1);   // boost key, unused (alpha >= 1)
  u32 nk0, nk1, xk0, xk1, uk0, uk1;
  jx_subkey(K0, K1, 3u, 0u, nk0, nk1);
  jx_subkey(K0, K1, 3u, 1u, xk0, xk1);
  jx_subkey(K0, K1, 3u, 2u, uk0, uk1);
  u32 c0 = xk0, c1 = xk1, t0, t1, s0, s1;
  jx_subkey(c0, c1, 2u, 0u, t0, t1);
  jx_subkey(c0, c1, 2u, 1u, s0, s1);
  const float x1 = normal_from_bits(jx_bits(s0, s1, 1u, 0u));
  c0 = t0; c1 = t1;
  jx_subkey(c0, c1, 2u, 0u, t0, t1);
  jx_subkey(c0, c1, 2u, 1u, s0, s1);
  const float x2 = normal_from_bits(jx_bits(s0, s1, 1u, 0u));
  const float U1 = u01_from_bits(jx_bits(uk0, uk1, 1u, 0u));
  float* R = RND + (size_t)i * 4;
  R[0] = z; R[1] = x1; R[2] = x2; R[3] = U1;
}

// ---------------- kernel 1: tscale + feature build ----------------
__global__ void __launch_bounds__(256) prep_kernel(
    const float* __restrict__ X, const float* __restrict__ emb,
    float* __restrict__ inp, float* __restrict__ ct,
    float* __restrict__ tscale, float* __restrict__ ltscale)
{
  const int b = blockIdx.x, t = threadIdx.x;
  __shared__ float red[256];
  __shared__ float ts_sh;
  const float* Xb = X + (size_t)b * LFULL * NCH;
  float p = fabsf(Xb[(28 + t) * NCH]);
  if (t < 80) p += fabsf(Xb[(28 + 256 + t) * NCH]);
  red[t] = p;
  for (int st = 128; st > 0; st >>= 1) { __syncthreads(); if (t < st) red[t] += red[t + st]; }
  __syncthreads();
  if (t == 0) {
    float ts = red[0] / 336.0f;
    ts = fmaxf(ts, 1e-10f);
    tscale[b] = ts; ltscale[b] = logf(ts); ts_sh = ts;
  }
  __syncthreads();
  const float ts = ts_sh;
  const float lts = logf(ts);
  const float ev = emb[0];
  for (int idx = t; idx < TM1 * NIN; idx += 256) {
    const int tt = idx / NIN, f = idx - tt * NIN;
    float val;
    if (f == 0)       val = (tt < CTX) ? Xb[(28 + tt) * NCH] / ts : 0.0f;
    else if (f <= 10) val = (tt < CTX) ? Xb[(28 + tt - c_LAGS[f - 1]) * NCH] / ts : 0.0f;
    else if (f == 11) val = ev;
    else if (f == 12) val = Xb[(28 + tt) * NCH + 2];
    else if (f == 13) val = lts;
    else              val = Xb[(28 + tt) * NCH + 1];
    inp[(size_t)(b * TM1 + tt) * NIN + f] = val;
    if (f == 0 && tt < CTX) ct[b * CTX + tt] = val;
  }
}

// ---------------- kernel 2: context LSTM (unchanged, exact fp32) -------------
__global__ void __launch_bounds__(256) ctx_lstm_kernel(
    const float* __restrict__ inp,
    const float* __restrict__ WTx, const float* __restrict__ WT00,
    const float* __restrict__ WT10, const float* __restrict__ WT11,
    const float* __restrict__ bih0, const float* __restrict__ bhh0,
    const float* __restrict__ bih1, const float* __restrict__ bhh1,
    const float* __restrict__ wdf, const float* __restrict__ bdfp,
    const float* __restrict__ wloc, const float* __restrict__ blocp,
    const float* __restrict__ wsc, const float* __restrict__ bscp,
    float* __restrict__ dfo, float* __restrict__ loco, float* __restrict__ sco,
    float* __restrict__ h0f, float* __restrict__ c0f,
    float* __restrict__ h1f, float* __restrict__ c1f)
{
  const int b = blockIdx.x, t = threadIdx.x;
  const int lane = t & 63, w = t >> 6;
  const int gbase = lane << 2;
  __shared__ __align__(16) float gA[4][256];
  __shared__ __align__(16) float gB[4][256];

  const float bs0 = bih0[lane]       + bhh0[lane];
  const float bs1 = bih0[64 + lane]  + bhh0[64 + lane];
  const float bs2 = bih0[128 + lane] + bhh0[128 + lane];
  const float bs3 = bih0[192 + lane] + bhh0[192 + lane];
  const float bs4 = bih1[lane]       + bhh1[lane];
  const float bs5 = bih1[64 + lane]  + bhh1[64 + lane];
  const float bs6 = bih1[128 + lane] + bhh1[128 + lane];
  const float bs7 = bih1[192 + lane] + bhh1[192 + lane];
  const float wdfv = wdf[lane], wlocv = wloc[lane], wscv = wsc[lane];
  const float bdf = bdfp[0], bloc = blocp[0], bsc = bscp[0];

  float h0r = 0.f, h1r = 0.f, c0r = 0.f, c1r = 0.f;
  const float* inb = inp + (size_t)b * TM1 * NIN;
  const int kx = w * 4;    // x-part k-quarter
  const int kh = w * 16;   // h-part k-quarter

  for (int tt = 0; tt < CTX; tt++) {
    float xr = 0.f;
    if (lane < 15) xr = inb[tt * NIN + lane];

    v2f aA = bc2(0.0f), aB = bc2(0.0f);
#pragma unroll
    for (int kk = 0; kk < 4; kk++) {
      const int k = kx + kk;
      const float4 wv = *(const float4*)&WTx[(k << 8) + gbase];
      v2f wlo, whi; wlo[0] = wv.x; wlo[1] = wv.y; whi[0] = wv.z; whi[1] = wv.w;
      const v2f hk = bc2(rl_f(xr, k));
      aA += wlo * hk; aB += whi * hk;
    }
#pragma unroll
    for (int kk = 0; kk < 16; kk++) {
      const int k = kh + kk;
      const float4 wv = *(const float4*)&WT00[(k << 8) + gbase];
      v2f wlo, whi; wlo[0] = wv.x; wlo[1] = wv.y; whi[0] = wv.z; whi[1] = wv.w;
      const v2f hk = bc2(rl_f(h0r, k));
      aA += wlo * hk; aB += whi * hk;
    }
    {
      float4 gv; gv.x = aA[0]; gv.y = aA[1]; gv.z = aB[0]; gv.w = aB[1];
      *(float4*)&gA[w][gbase] = gv;
    }
    __syncthreads();

    {
      float gi = ((gA[0][lane]       + gA[1][lane])       + gA[2][lane])       + gA[3][lane];
      float gf = ((gA[0][64 + lane]  + gA[1][64 + lane])  + gA[2][64 + lane])  + gA[3][64 + lane];
      float gg = ((gA[0][128 + lane] + gA[1][128 + lane]) + gA[2][128 + lane]) + gA[3][128 + lane];
      float go = ((gA[0][192 + lane] + gA[1][192 + lane]) + gA[2][192 + lane]) + gA[3][192 + lane];
      gi += bs0; gf += bs1; gg += bs2; go += bs3;
      c0r = sigm(gf) * c0r + sigm(gi) * tanhf(gg);
      h0r = sigm(go) * tanhf(c0r);
    }

    aA = bc2(0.0f); aB = bc2(0.0f);
#pragma unroll
    for (int kk = 0; kk < 16; kk++) {
      const int k = kh + kk;
      const float4 wv = *(const float4*)&WT10[(k << 8) + gbase];
      v2f wlo, whi; wlo[0] = wv.x; wlo[1] = wv.y; whi[0] = wv.z; whi[1] = wv.w;
      const v2f hk = bc2(rl_f(h0r, k));
      aA += wlo * hk; aB += whi * hk;
    }
#pragma unroll
    for (int kk = 0; kk < 16; kk++) {
      const int k = kh + kk;
      const float4 wv = *(const float4*)&WT11[(k << 8) + gbase];
      v2f wlo, whi; wlo[0] = wv.x; wlo[1] = wv.y; whi[0] = wv.z; whi[1] = wv.w;
      const v2f hk = bc2(rl_f(h1r, k));
      aA += wlo * hk; aB += whi * hk;
    }
    {
      float4 gv; gv.x = aA[0]; gv.y = aA[1]; gv.z = aB[0]; gv.w = aB[1];
      *(float4*)&gB[w][gbase] = gv;
    }
    __syncthreads();

    {
      float gi = ((gB[0][lane]       + gB[1][lane])       + gB[2][lane])       + gB[3][lane];
      float gf = ((gB[0][64 + lane]  + gB[1][64 + lane])  + gB[2][64 + lane])  + gB[3][64 + lane];
      float gg = ((gB[0][128 + lane] + gB[1][128 + lane]) + gB[2][128 + lane]) + gB[3][128 + lane];
      float go = ((gB[0][192 + lane] + gB[1][192 + lane]) + gB[2][192 + lane]) + gB[3][192 + lane];
      gi += bs4; gf += bs5; gg += bs6; go += bs7;
      c1r = sigm(gf) * c1r + sigm(gi) * tanhf(gg);
      h1r = sigm(go) * tanhf(c1r);
      if (w == 0) {
        float pd = h1r * wdfv, pl = h1r * wlocv, ps = h1r * wscv;
#pragma unroll
        for (int off = 32; off > 0; off >>= 1) {
          pd += __shfl_down(pd, off, 64);
          pl += __shfl_down(pl, off, 64);
          ps += __shfl_down(ps, off, 64);
        }
        if (lane == 0) {
          dfo[b * CTX + tt]  = 2.0f + softplusf(pd + bdf);
          loco[b * CTX + tt] = pl + bloc;
          sco[b * CTX + tt]  = softplusf(ps + bsc);
        }
      }
    }
  }
  if (w == 0) {
    h0f[b * 64 + lane] = h0r; c0f[b * 64 + lane] = c0r;
    h1f[b * 64 + lane] = h1r; c1f[b * 64 + lane] = c1r;
  }
}

// ---------------- kernel 3: context sampling (y_ctx) ----------------
__global__ void __launch_bounds__(256) ctx_sample_kernel(
    const float* __restrict__ df, const float* __restrict__ loc, const float* __restrict__ sc,
    const float* __restrict__ tscale, float* __restrict__ yhat,
    u32 kz0, u32 kz1, u32 kg0, u32 kg1)
{
  const int i = blockIdx.x * 256 + threadIdx.x;
  const int r = i / CTX, t = i - r * CTX;
  const int b = r / NSAMP;
  const float dfv = df[b * CTX + t], lv = loc[b * CTX + t], sv = sc[b * CTX + t];
  const float z = normal_from_bits(jx_bits(kz0, kz1, NCTXS, (u32)i));
  u32 gk0, gk1;
  jx_subkey(kg0, kg1, NCTXS, (u32)i, gk0, gk1);
  const float g = jax_gamma_one(gk0, gk1, dfv * 0.5f);
  const float y = (lv + sv * (z * sqrtf(dfv / (2.0f * g)))) * tscale[b];
  yhat[(size_t)r * TM1 + t] = y;
}

// ---------------- kernel 5: persistent decode (MFMA, verified shape only) ----
// R4: R3's layout logic was k-permutation-invariant (same placement function
// for A and B), so the failure is pinned on the ONLY instruction outside the
// m89/m97-verified set: the legacy 16x16x16f16 used for the x-part.  Fix:
// x-part becomes a zero-padded 16x16x32_f16 (xh padded to 32 with hard zeros;
// x B-fragments store only the k<16 lanes, overflow reads are killed by zero
// A elements).  Everything else identical to R3.
__global__ void __launch_bounds__(512) dec_persist_kernel(
    const float* __restrict__ inp, const float* __restrict__ tscale,
    const f16* __restrict__ WH,
    const float* __restrict__ bih0, const float* __restrict__ bhh0,
    const float* __restrict__ bih1, const float* __restrict__ bhh1,
    const float* __restrict__ wdf, const float* __restrict__ bdfp,
    const float* __restrict__ wloc, const float* __restrict__ blocp,
    const float* __restrict__ wsc, const float* __restrict__ bscp,
    const float* __restrict__ h0f, const float* __restrict__ c0f,
    const float* __restrict__ h1f, const float* __restrict__ c1f,
    const float* __restrict__ ct, const float* __restrict__ RND,
    float* __restrict__ yhat, u32 kl0, u32 kl1)
{
  const int t    = threadIdx.x;
  const int lane = t & 63;
  const int w    = t >> 6;        // wave 0..7
  const int r0   = w * RPW;       // wave's first local row
  const int c16  = lane & 15;     // gate col within tile / A row select
  const int kg   = lane >> 4;     // k-group / D row-group

  __shared__ __align__(16) f16   wgt[WH_TOT];        // 104 KB B-fragment weights
  __shared__ __align__(16) f16   h0h[DROWS * HSTR];  // 18 KB
  __shared__ __align__(16) f16   h1h[DROWS * HSTR];  // 18 KB
  __shared__ __align__(16) f16   xh[DROWS][32];      // 8 KB (slots 15..31 = 0)
  __shared__ __align__(16) f16   hist[DROWS][32];    // 8 KB lag ring
  __shared__ __align__(16) f16   fst[3][NSTEP][4];   // 1.1 KB feature stash
  __shared__ float prevs[DROWS], tsr[DROWS];
  __shared__ float dfL[DROWS], locL[DROWS], scL[DROWS];
  __shared__ unsigned char rsel[DROWS];

  const int base = blockIdx.x * DROWS;
  const int bblo = base / NSAMP;

  // ---- stage all weights once: 13 x (8 waves x 64 lanes x 16B) ----
#pragma unroll
  for (int i = 0; i < 13; i++) {
    const int off = (i * 8 + w) * 512;   // halves
    __builtin_amdgcn_global_load_lds(
        (const __attribute__((address_space(1))) void*)(WH + off + lane * 8),
        (__attribute__((address_space(3))) void*)(wgt + off), 16, 0, 0);
  }

  // ---- per-lane constants: biases / head weights / c-state ----
  float b0[4][4], b1[4][4];
#pragma unroll
  for (int gq = 0; gq < 4; gq++)
#pragma unroll
    for (int tq = 0; tq < 4; tq++) {
      const int g = gq * 64 + tq * 16 + c16;
      b0[gq][tq] = bih0[g] + bhh0[g];
      b1[gq][tq] = bih1[g] + bhh1[g];
    }
  float wd[4], wl[4], wsv[4];
#pragma unroll
  for (int tq = 0; tq < 4; tq++) {
    wd[tq]  = wdf[tq * 16 + c16];
    wl[tq]  = wloc[tq * 16 + c16];
    wsv[tq] = wsc[tq * 16 + c16];
  }
  const float bdf = bdfp[0], bloc = blocp[0], bsc = bscp[0];

  float c0reg[4][4], c1reg[4][4];
#pragma unroll
  for (int rr = 0; rr < 4; rr++) {
    const int row = r0 + kg * 4 + rr;
    const int bb = (base + row) / NSAMP;
#pragma unroll
    for (int tq = 0; tq < 4; tq++) {
      c0reg[rr][tq] = c0f[bb * 64 + tq * 16 + c16];
      c1reg[rr][tq] = c1f[bb * 64 + tq * 16 + c16];
    }
  }

  // ---- h state into LDS (stride HSTR) ----
  for (int idx = t; idx < DROWS * 64; idx += 512) {
    const int row = idx >> 6, hid = idx & 63;
    const int bb = (base + row) / NSAMP;
    h0h[row * HSTR + hid] = (f16)h0f[bb * 64 + hid];
    h1h[row * HSTR + hid] = (f16)h1f[bb * 64 + hid];
  }

  for (int idx = t; idx < DROWS * 28; idx += 512) {
    const int i = idx / 28, k = idx - i * 28;
    const int bb = (base + i) / NSAMP;
    hist[i][31 - k] = (f16)ct[bb * CTX + 335 - k];
  }
  // feature stash: rows of a 128-row block span at most 2 batch indices
  for (int idx = t; idx < 3 * NSTEP * 4; idx += 512) {
    const int sel = idx / (NSTEP * 4), rem = idx - sel * (NSTEP * 4);
    const int s = rem >> 2, f = rem & 3;
    const int bb = min(bblo + sel, NB - 1);
    fst[sel][s][f] = (f16)inp[((size_t)bb * TM1 + CTX + s) * NIN + 11 + f];
  }
  if (t < DROWS) {
    const int rg = base + t;
    prevs[t] = yhat[(size_t)rg * TM1 + 335];
    tsr[t] = tscale[rg / NSAMP];
    for (int j = 15; j < 32; j++) xh[t][j] = (f16)0.0f;  // hard-zero K pad
    rsel[t] = (unsigned char)((rg / NSAMP) - bblo);
  }
  __syncthreads();   // covers weight staging (vmcnt drain) + all init writes

  const int arow = r0 + c16;         // A-fragment row for this lane

  for (int s = 0; s < NSTEP; s++) {
    // ---- prefetch this step's randoms ----
    float rz = 0.f, rx1 = 0.f, rx2 = 0.f, rU = 0.f;
    if (lane < RPW) {
      const float4 R = *(const float4*)(RND + ((size_t)s * RTOT + base + r0 + lane) * 4);
      rz = R.x; rx1 = R.y; rx2 = R.z; rU = R.w;
    }

    // ---- parallel x-build (slots 0..14; 15..31 stay zero) ----
    if (lane < RPW) {
      const int row = r0 + lane;
      const float nv = prevs[row] / tsr[row];
      const f16 nh = (f16)nv;
      xh[row][0] = nh;
      hist[row][s & 31] = nh;
    }
    {
      const int rq = lane >> 2, q = lane & 3;
      const int row = r0 + rq;
#pragma unroll
      for (int p = 0; p < 4; p++) {
        const int sl = 1 + q + p * 4;          // 1..16
        if (sl <= 10) {
          xh[row][sl] = hist[row][(s - c_LAGS[sl - 1]) & 31];
        } else if (sl <= 14) {
          xh[row][sl] = fst[rsel[row]][s][sl - 11];
        }
      }
    }

    // ---- layer 0: A-frags + 48 MFMAs (all 16x16x32_f16) ----
    const half8 ax  = *(const half8*)&xh[arow][kg * 8];
    const half8 a00 = *(const half8*)&h0h[arow * HSTR + kg * 8];
    const half8 a01 = *(const half8*)&h0h[arow * HSTR + 32 + kg * 8];
    floatx4 acc[16];
#pragma unroll
    for (int nt = 0; nt < 16; nt++) {
      floatx4 a = {0.f, 0.f, 0.f, 0.f};
      a = __builtin_amdgcn_mfma_f32_16x16x32_f16(
            ax, *(const half8*)&wgt[WH_X + nt * 256 + lane * 8], a, 0, 0, 0);
      a = __builtin_amdgcn_mfma_f32_16x16x32_f16(
            a00, *(const half8*)&wgt[WH_00 + (nt * 2 + 0) * 512 + lane * 8], a, 0, 0, 0);
      a = __builtin_amdgcn_mfma_f32_16x16x32_f16(
            a01, *(const half8*)&wgt[WH_00 + (nt * 2 + 1) * 512 + lane * 8], a, 0, 0, 0);
      acc[nt] = a;
    }

    // ---- cell 0 (lane-local i/f/g/o per hid) ----
#pragma unroll
    for (int rr = 0; rr < 4; rr++) {
      const int row = r0 + kg * 4 + rr;
#pragma unroll
      for (int tq = 0; tq < 4; tq++) {
        const float gi = acc[tq][rr]      + b0[0][tq];
        const float gf = acc[4 + tq][rr]  + b0[1][tq];
        const float gg = acc[8 + tq][rr]  + b0[2][tq];
        const float go = acc[12 + tq][rr] + b0[3][tq];
        float cc = c0reg[rr][tq];
        cc = sigm(gf) * cc + sigm(gi) * tanhf(gg);
        c0reg[rr][tq] = cc;
        h0h[row * HSTR + tq * 16 + c16] = (f16)(sigm(go) * tanhf(cc));
      }
    }

    // ---- layer 1: A-frags + 64 MFMAs ----
    const half8 a10a = *(const half8*)&h0h[arow * HSTR + kg * 8];
    const half8 a10b = *(const half8*)&h0h[arow * HSTR + 32 + kg * 8];
    const half8 a11a = *(const half8*)&h1h[arow * HSTR + kg * 8];
    const half8 a11b = *(const half8*)&h1h[arow * HSTR + 32 + kg * 8];
#pragma unroll
    for (int nt = 0; nt < 16; nt++) {
      floatx4 a = {0.f, 0.f, 0.f, 0.f};
      a = __builtin_amdgcn_mfma_f32_16x16x32_f16(
            a10a, *(const half8*)&wgt[WH_10 + (nt * 2 + 0) * 512 + lane * 8], a, 0, 0, 0);
      a = __builtin_amdgcn_mfma_f32_16x16x32_f16(
            a10b, *(const half8*)&wgt[WH_10 + (nt * 2 + 1) * 512 + lane * 8], a, 0, 0, 0);
      a = __builtin_amdgcn_mfma_f32_16x16x32_f16(
            a11a, *(const half8*)&wgt[WH_11 + (nt * 2 + 0) * 512 + lane * 8], a, 0, 0, 0);
      a = __builtin_amdgcn_mfma_f32_16x16x32_f16(
            a11b, *(const half8*)&wgt[WH_11 + (nt * 2 + 1) * 512 + lane * 8], a, 0, 0, 0);
      acc[nt] = a;
    }

    // ---- cell 1 + head partials ----
    float pd[4], pl[4], ps[4];
#pragma unroll
    for (int rr = 0; rr < 4; rr++) { pd[rr] = 0.f; pl[rr] = 0.f; ps[rr] = 0.f; }
#pragma unroll
    for (int rr = 0; rr < 4; rr++) {
      const int row = r0 + kg * 4 + rr;
#pragma unroll
      for (int tq = 0; tq < 4; tq++) {
        const float gi = acc[tq][rr]      + b1[0][tq];
        const float gf = acc[4 + tq][rr]  + b1[1][tq];
        const float gg = acc[8 + tq][rr]  + b1[2][tq];
        const float go = acc[12 + tq][rr] + b1[3][tq];
        float cc = c1reg[rr][tq];
        cc = sigm(gf) * cc + sigm(gi) * tanhf(gg);
        c1reg[rr][tq] = cc;
        const float h1v = sigm(go) * tanhf(cc);
        h1h[row * HSTR + tq * 16 + c16] = (f16)h1v;
        pd[rr] += h1v * wd[tq];
        pl[rr] += h1v * wl[tq];
        ps[rr] += h1v * wsv[tq];
      }
    }
    // reduce across the 16 cols (lanes share kg within width-16 groups)
#pragma unroll
    for (int rr = 0; rr < 4; rr++) {
#pragma unroll
      for (int off = 8; off >= 1; off >>= 1) {
        pd[rr] += __shfl_xor(pd[rr], off, 16);
        pl[rr] += __shfl_xor(pl[rr], off, 16);
        ps[rr] += __shfl_xor(ps[rr], off, 16);
      }
    }
    if (c16 == 0) {
#pragma unroll
      for (int rr = 0; rr < 4; rr++) {
        const int row = r0 + kg * 4 + rr;
        dfL[row]  = 2.0f + softplusf(pd[rr] + bdf);
        locL[row] = pl[rr] + bloc;
        scL[row]  = softplusf(ps[rr] + bsc);
      }
    }

    // ---- sample (one lane per row, 16 rows in parallel) ----
    if (lane < RPW) {
      const int row = r0 + lane, rg = base + row;
      const float dfv = dfL[row], lv = locL[row], scv = scL[row];
      const float z = rz;
      const float alpha = dfv * 0.5f;
      float gam;
      {
#pragma clang fp contract(off)
        const float d = alpha - 0.33333334f;
        const float c = 0.33333334f / sqrtf(d);
        float x = rx1;
        float v = 1.0f + x * c;
        bool ok = true;
        if (v <= 0.0f) { x = rx2; v = 1.0f + x * c; ok = (v > 0.0f); }
        const float X = x * x;
        const float V = (v * v) * v;
        const float U = rU;
        bool accept = false;
        if (ok) {
          if (!(U >= 1.0f - 0.0331f * (X * X))) accept = true;
          else if (!(logf(U) >= 0.5f * X + d * ((1.0f - V) + logf(V)))) accept = true;
        }
        if (accept) {
          gam = d * V;
        } else {
          u32 ks0, ks1, skg0, skg1, gk0, gk1;
          tf2x32(kl0, kl1, 0u, (u32)s, ks0, ks1);
          tf2x32(ks0, ks1, 0u, 1u, skg0, skg1);
          jx_subkey(skg0, skg1, RTOT, (u32)rg, gk0, gk1);
          gam = jax_gamma_one(gk0, gk1, alpha);
        }
      }
      const float y = (lv + scv * (z * sqrtf(dfv / (2.0f * gam)))) * tsr[row];
      yhat[(size_t)rg * TM1 + CTX + s] = y;
      prevs[row] = y;
    }
  }
}

// ---------------- kernel 6: median over 100 samples per (b,t) ----------------
__global__ void __launch_bounds__(256) median_kernel(
    const float* __restrict__ yhat, float* __restrict__ out)
{
  __shared__ float vals[4][100];
  const int wave = threadIdx.x >> 6, lane = threadIdx.x & 63;
  const int cell = blockIdx.x * 4 + wave;
  const int b = cell / TM1, t = cell - b * TM1;
  const float* basep = yhat + (size_t)b * NSAMP * TM1 + t;
  const float v1 = basep[(size_t)lane * TM1];
  vals[wave][lane] = v1;
  float v2 = 0.f;
  if (lane < 36) { v2 = basep[(size_t)(64 + lane) * TM1]; vals[wave][64 + lane] = v2; }
  __syncthreads();
  int cl1 = 0, ce1 = 0, cl2 = 0, ce2 = 0;
  for (int jj = 0; jj < 100; jj++) {
    const float w = vals[wave][jj];
    cl1 += (w < v1); ce1 += (w == v1);
    cl2 += (w < v2); ce2 += (w == v2);
  }
  if (cl1 <= 49 && 49 < cl1 + ce1) out[cell] = v1;
  if (lane < 36 && cl2 <= 49 && 49 < cl2 + ce2) out[cell] = v2;
}

// ---------------- launch ----------------
extern "C" void kernel_launch(void* const* d_in, const int* in_sizes, int n_in,
                              void* d_out, int out_size, void* d_ws, size_t ws_size,
                              hipStream_t stream) {
  (void)in_sizes; (void)n_in; (void)out_size; (void)ws_size;
  const float* X     = (const float*)d_in[0];
  const float* Wih0  = (const float*)d_in[2];
  const float* Whh0  = (const float*)d_in[3];
  const float* bih0  = (const float*)d_in[4];
  const float* bhh0  = (const float*)d_in[5];
  const float* Wih1  = (const float*)d_in[6];
  const float* Whh1  = (const float*)d_in[7];
  const float* bih1  = (const float*)d_in[8];
  const float* bhh1  = (const float*)d_in[9];
  const float* wdf   = (const float*)d_in[10];
  const float* bdf   = (const float*)d_in[11];
  const float* wloc  = (const float*)d_in[12];
  const float* bloc  = (const float*)d_in[13];
  const float* wsc   = (const float*)d_in[14];
  const float* bsc   = (const float*)d_in[15];
  const float* emb   = (const float*)d_in[16];

  float* wsf = (float*)d_ws;
  float* inp  = wsf + OFF_INP;
  float* ct   = wsf + OFF_CT;
  float* ts   = wsf + OFF_TS;
  float* lts  = wsf + OFF_LTS;
  float* dfp  = wsf + OFF_DF;
  float* locp = wsf + OFF_LOC;
  float* scp  = wsf + OFF_SC;
  float* h0f  = wsf + OFF_H0F;
  float* c0f  = wsf + OFF_C0F;
  float* h1f  = wsf + OFF_H1F;
  float* c1f  = wsf + OFF_C1F;
  float* yhat = wsf + OFF_YH;
  float* wtx  = wsf + OFF_WTX;
  float* wt00 = wsf + OFF_WT00;
  float* wt10 = wsf + OFF_WT10;
  float* wt11 = wsf + OFF_WT11;
  f16*   wh   = (f16*)(wsf + OFF_WH);
  float* rnd  = wsf + OFF_RND;

  const u32 key0 = 0u, key1 = 42u;
  u32 kc0, kc1, kl0, kl1;
  jx_subkey(key0, key1, 2u, 0u, kc0, kc1);
  jx_subkey(key0, key1, 2u, 1u, kl0, kl1);
  u32 kz0, kz1, kg0, kg1;
  jx_subkey(kc0, kc1, 2u, 0u, kz0, kz1);
  jx_subkey(kc0, kc1, 2u, 1u, kg0, kg1);

  wtrans_kernel<<<208, 256, 0, stream>>>(Wih0, Whh0, Wih1, Whh1, wtx, wt00, wt10, wt11);
  wh_kernel<<<208, 256, 0, stream>>>(Wih0, Whh0, Wih1, Whh1, wh);
  rnd_dec_kernel<<<(NSTEP * RTOT) / 256, 256, 0, stream>>>(rnd, kl0, kl1);
  prep_kernel<<<NB, 256, 0, stream>>>(X, emb, inp, ct, ts, lts);
  ctx_lstm_kernel<<<NB, 256, 0, stream>>>(inp, wtx, wt00, wt10, wt11,
                                          bih0, bhh0, bih1, bhh1,
                                          wdf, bdf, wloc, bloc, wsc, bsc,
                                          dfp, locp, scp, h0f, c0f, h1f, c1f);
  ctx_sample_kernel<<<NCTXS / 256, 256, 0, stream>>>(dfp, locp, scp, ts, yhat, kz0, kz1, kg0, kg1);
  dec_persist_kernel<<<DBLOCKS, 512, 0, stream>>>(inp, ts, wh,
                                                  bih0, bhh0, bih1, bhh1,
                                                  wdf, bdf, wloc, bloc, wsc, bsc,
                                                  h0f, c0f, h1f, c1f, ct, rnd, yhat, kl0, kl1);
  median_kernel<<<(NB * TM1) / 4, 256, 0, stream>>>(yhat, (float*)d_out);
}